// Round 1
// baseline (8811.029 us; speedup 1.0000x reference)
//
#include <hip/hip_runtime.h>
#include <cstdint>
#include <cstddef>

#define N_NODES 50000
#define N_EDGES 1600000
#define N_META  3
#define DIM     128

// ws layout (floats):
//   z_raw  : [M][N][D]  (un-normalized aggregation, norm_dst applied on read)
//   deg_out: [M][N]
//   deg_in : [M][N]
//   wacc   : [16]       (semantic-attention score accumulators, 3 used)

// ---------------------------------------------------------------- degrees ---
// blockIdx.y = slice s in [0,6): m = s>>1, role = s&1 (0=src->out_deg, 1=dst->in_deg)
__global__ void deg_kernel(const int* __restrict__ edges, float* __restrict__ deg) {
    const int s    = blockIdx.y;
    const int m    = s >> 1;
    const int role = s & 1;
    const int* ids = edges + (size_t)s * N_EDGES;
    float* d = deg + ((size_t)role * N_META + m) * N_NODES;
    int i = blockIdx.x * blockDim.x + threadIdx.x;
    const int stride = gridDim.x * blockDim.x;
    for (; i < N_EDGES; i += stride)
        atomicAdd(&d[ids[i]], 1.0f);
}

// ---------------------------------------------------------------- scatter ---
// 32 lanes per edge, each lane handles 4 consecutive floats (float4 gather,
// 4x atomicAdd scatter). blockIdx.y = metapath.
__global__ __launch_bounds__(256) void scatter_kernel(
        const float* __restrict__ h, const int* __restrict__ edges,
        const float* __restrict__ deg_out, float* __restrict__ z) {
    const int m    = blockIdx.y;
    const int lane = threadIdx.x & 31;
    const int grp  = (blockIdx.x * blockDim.x + threadIdx.x) >> 5;
    const int gstr = (gridDim.x * blockDim.x) >> 5;
    const int* src_ids = edges + (size_t)(m * 2) * N_EDGES;
    const int* dst_ids = src_ids + N_EDGES;
    const float* dO = deg_out + (size_t)m * N_NODES;
    float* zm = z + (size_t)m * N_NODES * DIM;
    for (int e = grp; e < N_EDGES; e += gstr) {
        const int src = src_ids[e];
        const int dst = dst_ids[e];
        const float ns = rsqrtf(fmaxf(dO[src], 1.0f));
        const float4 hv = *reinterpret_cast<const float4*>(h + (size_t)src * DIM + lane * 4);
        float* zp = zm + (size_t)dst * DIM + lane * 4;
        atomicAdd(zp + 0, hv.x * ns);
        atomicAdd(zp + 1, hv.y * ns);
        atomicAdd(zp + 2, hv.z * ns);
        atomicAdd(zp + 3, hv.w * ns);
    }
}

// -------------------------------------------------------------- attention ---
// Per metapath (blockIdx.y), compute sum over nodes of tanh(z_n @ W1 + b1) @ W2.
// Block = 128 threads (thread j owns output column j). 8 nodes processed per
// pass: z reads are wave-uniform (scalar-load pipe), W1 read is one coalesced
// vector load shared by all 8 nodes' FMAs. norm_dst folded in AFTER the
// dot-product (q_scaled = q * rsqrt(in_deg)).
__global__ __launch_bounds__(128) void attn_kernel(
        const float* __restrict__ z, const float* __restrict__ deg_in,
        const float* __restrict__ W1, const float* __restrict__ b1,
        const float* __restrict__ W2, float* __restrict__ wacc) {
    const int m   = blockIdx.y;
    const int tid = threadIdx.x;
    __shared__ float red[128];
    const float* zm = z + (size_t)m * N_NODES * DIM;
    const float* dI = deg_in + (size_t)m * N_NODES;
    const float bj  = b1[tid];
    const float w2j = W2[tid];
    float acc = 0.0f;
    // 6250 groups of 8 nodes; grid.x = 625 -> exactly 10 groups per block.
    for (int g = blockIdx.x; g < (N_NODES / 8); g += gridDim.x) {
        const int nbase = g * 8;
        float sc[8];
#pragma unroll
        for (int u = 0; u < 8; ++u)
            sc[u] = rsqrtf(fmaxf(dI[nbase + u], 1.0f));
        float q[8] = {0.f, 0.f, 0.f, 0.f, 0.f, 0.f, 0.f, 0.f};
#pragma unroll 4
        for (int d = 0; d < DIM; ++d) {
            const float w1v = W1[d * DIM + tid];   // coalesced vector load (L1)
#pragma unroll
            for (int u = 0; u < 8; ++u) {
                const float zr = zm[(size_t)(nbase + u) * DIM + d];  // uniform -> s_load
                q[u] = fmaf(zr, w1v, q[u]);
            }
        }
#pragma unroll
        for (int u = 0; u < 8; ++u)
            acc += tanhf(fmaf(q[u], sc[u], bj)) * w2j;
    }
    red[tid] = acc;
    __syncthreads();
    for (int s = 64; s > 0; s >>= 1) {
        if (tid < s) red[tid] += red[tid + s];
        __syncthreads();
    }
    if (tid == 0) atomicAdd(&wacc[m], red[0]);
}

// ---------------------------------------------------------------- epilogue --
// beta = softmax(wacc / N) computed inline; out[n,:] = sum_m beta_m * norm_dst * z_raw.
__global__ __launch_bounds__(256) void final_kernel(
        const float* __restrict__ z, const float* __restrict__ deg_in,
        const float* __restrict__ wacc, float* __restrict__ out) {
    const int g = blockIdx.x * blockDim.x + threadIdx.x;  // float4 index
    if (g >= N_NODES * DIM / 4) return;
    const int n = g >> 5;   // 32 float4 per node row
    const float invN = 1.0f / (float)N_NODES;
    const float w0 = wacc[0] * invN, w1 = wacc[1] * invN, w2 = wacc[2] * invN;
    const float mx = fmaxf(w0, fmaxf(w1, w2));
    const float e0 = expf(w0 - mx), e1 = expf(w1 - mx), e2 = expf(w2 - mx);
    const float inv = 1.0f / (e0 + e1 + e2);
    const float beta[3] = {e0 * inv, e1 * inv, e2 * inv};
    float4 acc = {0.f, 0.f, 0.f, 0.f};
#pragma unroll
    for (int m = 0; m < N_META; ++m) {
        const float sc = rsqrtf(fmaxf(deg_in[(size_t)m * N_NODES + n], 1.0f)) * beta[m];
        const float4 zv = *reinterpret_cast<const float4*>(
            z + ((size_t)m * N_NODES) * DIM + (size_t)g * 4);
        acc.x = fmaf(zv.x, sc, acc.x);
        acc.y = fmaf(zv.y, sc, acc.y);
        acc.z = fmaf(zv.z, sc, acc.z);
        acc.w = fmaf(zv.w, sc, acc.w);
    }
    *reinterpret_cast<float4*>(out + (size_t)g * 4) = acc;
}

extern "C" void kernel_launch(void* const* d_in, const int* in_sizes, int n_in,
                              void* d_out, int out_size, void* d_ws, size_t ws_size,
                              hipStream_t stream) {
    const float* h    = (const float*)d_in[0];
    const int*  edges = (const int*)d_in[1];
    const float* W1   = (const float*)d_in[2];
    const float* b1   = (const float*)d_in[3];
    const float* W2   = (const float*)d_in[4];
    float* out = (float*)d_out;

    float* ws      = (float*)d_ws;
    float* z       = ws;                                         // M*N*D
    float* deg     = ws + (size_t)N_META * N_NODES * DIM;        // deg_out | deg_in
    float* deg_out = deg;
    float* deg_in  = deg + (size_t)N_META * N_NODES;
    float* wacc    = deg_in + (size_t)N_META * N_NODES;

    const size_t zero_bytes =
        ((size_t)N_META * N_NODES * DIM + 2 * (size_t)N_META * N_NODES + 16) * sizeof(float);
    hipMemsetAsync(d_ws, 0, zero_bytes, stream);

    deg_kernel<<<dim3(1024, 6), dim3(256), 0, stream>>>(edges, deg);
    scatter_kernel<<<dim3(4096, 3), dim3(256), 0, stream>>>(h, edges, deg_out, z);
    attn_kernel<<<dim3(625, 3), dim3(128), 0, stream>>>(z, deg_in, W1, b1, W2, wacc);
    final_kernel<<<dim3((N_NODES * DIM / 4) / 256, 1), dim3(256), 0, stream>>>(
        z, deg_in, wacc, out);
}

// Round 2
// 1512.294 us; speedup vs baseline: 5.8263x; 5.8263x over previous
//
#include <hip/hip_runtime.h>
#include <cstdint>
#include <cstddef>

#define N_NODES 50000
#define N_EDGES 1600000
#define N_META  3
#define DIM     128
#define SCAN_T  1024
#define SEG     ((N_NODES + SCAN_T - 1) / SCAN_T)   // 49

// ws layout (4-byte units), in order:
//   z       : [M][N][D] float   (un-normalized aggregation)
//   wacc    : [16] float        (semantic-attention accumulators; zeroed)
//   out_cnt : [M][N] int        (zeroed)
//   in_cnt  : [M][N] int        (zeroed)
//   nsrc    : [M][N] float      (rsqrt(max(out_deg,1)))
//   ndst    : [M][N] float
//   row_off : [M][N+1] int  (padded to M*(N+1)+13 for alignment)
//   cursor  : [M][N] int
//   csr     : [M][E] int        (src ids grouped by dst)

// ---------------------------------------------------------------- degrees ---
// blockIdx.y = s in [0,6): m = s>>1, role = s&1 (0=src->out_cnt, 1=dst->in_cnt)
__global__ void deg_kernel(const int* __restrict__ edges,
                           int* __restrict__ out_cnt, int* __restrict__ in_cnt) {
    const int s    = blockIdx.y;
    const int m    = s >> 1;
    const int role = s & 1;
    const int* ids = edges + (size_t)s * N_EDGES;
    int* cnt = (role ? in_cnt : out_cnt) + m * N_NODES;
    int i = blockIdx.x * blockDim.x + threadIdx.x;
    const int stride = gridDim.x * blockDim.x;
    for (; i < N_EDGES; i += stride)
        atomicAdd(&cnt[ids[i]], 1);
}

// ------------------------------------------------------------------ norms ---
__global__ void norm_kernel(const int* __restrict__ out_cnt, const int* __restrict__ in_cnt,
                            float* __restrict__ nsrc, float* __restrict__ ndst) {
    const int i = blockIdx.x * blockDim.x + threadIdx.x;
    if (i >= N_META * N_NODES) return;
    nsrc[i] = rsqrtf(fmaxf((float)out_cnt[i], 1.0f));
    ndst[i] = rsqrtf(fmaxf((float)in_cnt[i], 1.0f));
}

// ------------------------------------------------------------------- scan ---
// One block (1024 threads) per metapath: exclusive scan of in_cnt -> row_off, cursor.
__global__ __launch_bounds__(SCAN_T) void scan_kernel(
        const int* __restrict__ in_cnt, int* __restrict__ row_off, int* __restrict__ cursor) {
    const int m = blockIdx.x;
    const int t = threadIdx.x;
    const int* cnt = in_cnt + m * N_NODES;
    int* ro  = row_off + m * (N_NODES + 1);
    int* cur = cursor + m * N_NODES;
    const int beg = t * SEG;
    const int end = min(beg + SEG, N_NODES);
    int sum = 0;
    for (int i = beg; i < end; ++i) sum += cnt[i];
    __shared__ int part[SCAN_T];
    part[t] = sum;
    __syncthreads();
    for (int off = 1; off < SCAN_T; off <<= 1) {
        const int v = (t >= off) ? part[t - off] : 0;
        __syncthreads();
        part[t] += v;
        __syncthreads();
    }
    int pref = part[t] - sum;   // exclusive prefix of this thread's segment
    for (int i = beg; i < end; ++i) {
        ro[i]  = pref;
        cur[i] = pref;
        pref += cnt[i];
    }
    if (t == 0) ro[N_NODES] = N_EDGES;
}

// ------------------------------------------------------------------- fill ---
__global__ void fill_kernel(const int* __restrict__ edges,
                            int* __restrict__ cursor, int* __restrict__ csr) {
    const int m = blockIdx.y;
    const int* src_ids = edges + (size_t)(m * 2) * N_EDGES;
    const int* dst_ids = src_ids + N_EDGES;
    int* cur = cursor + m * N_NODES;
    int* row = csr + (size_t)m * N_EDGES;
    int i = blockIdx.x * blockDim.x + threadIdx.x;
    const int stride = gridDim.x * blockDim.x;
    for (; i < N_EDGES; i += stride) {
        const int pos = atomicAdd(&cur[dst_ids[i]], 1);
        row[pos] = src_ids[i];
    }
}

// ----------------------------------------------------------------- gather ---
// One wave (64 lanes) per dst node; lane owns 2 of 128 dims. Per edge: broadcast
// id + norm load, coalesced 512B float2 read of h, register accumulate. One
// plain float2 store per output row -> zero float atomics.
__global__ __launch_bounds__(256) void gather_kernel(
        const float* __restrict__ h, const int* __restrict__ csr,
        const int* __restrict__ row_off, const float* __restrict__ nsrc,
        float* __restrict__ z) {
    const int m    = blockIdx.y;
    const int wave = threadIdx.x >> 6;
    const int lane = threadIdx.x & 63;
    const int node = blockIdx.x * 4 + wave;          // 12500*4 == N_NODES exactly
    const int* ro = row_off + m * (N_NODES + 1);
    const int beg = ro[node];
    const int end = ro[node + 1];
    const int* srcs = csr + (size_t)m * N_EDGES;
    const float* ns = nsrc + m * N_NODES;
    float2 acc = {0.0f, 0.0f};
    int j = beg;
    for (; j + 4 <= end; j += 4) {
        const int s0 = srcs[j], s1 = srcs[j + 1], s2 = srcs[j + 2], s3 = srcs[j + 3];
        const float n0 = ns[s0], n1 = ns[s1], n2 = ns[s2], n3 = ns[s3];
        const float2 h0 = *reinterpret_cast<const float2*>(h + (size_t)s0 * DIM + lane * 2);
        const float2 h1 = *reinterpret_cast<const float2*>(h + (size_t)s1 * DIM + lane * 2);
        const float2 h2 = *reinterpret_cast<const float2*>(h + (size_t)s2 * DIM + lane * 2);
        const float2 h3 = *reinterpret_cast<const float2*>(h + (size_t)s3 * DIM + lane * 2);
        acc.x = fmaf(h0.x, n0, acc.x); acc.y = fmaf(h0.y, n0, acc.y);
        acc.x = fmaf(h1.x, n1, acc.x); acc.y = fmaf(h1.y, n1, acc.y);
        acc.x = fmaf(h2.x, n2, acc.x); acc.y = fmaf(h2.y, n2, acc.y);
        acc.x = fmaf(h3.x, n3, acc.x); acc.y = fmaf(h3.y, n3, acc.y);
    }
    for (; j < end; ++j) {
        const int s0 = srcs[j];
        const float n0 = ns[s0];
        const float2 h0 = *reinterpret_cast<const float2*>(h + (size_t)s0 * DIM + lane * 2);
        acc.x = fmaf(h0.x, n0, acc.x); acc.y = fmaf(h0.y, n0, acc.y);
    }
    *reinterpret_cast<float2*>(z + ((size_t)m * N_NODES + node) * DIM + lane * 2) = acc;
}

// -------------------------------------------------------------- attention ---
__global__ __launch_bounds__(128) void attn_kernel(
        const float* __restrict__ z, const float* __restrict__ ndst,
        const float* __restrict__ W1, const float* __restrict__ b1,
        const float* __restrict__ W2, float* __restrict__ wacc) {
    const int m   = blockIdx.y;
    const int tid = threadIdx.x;
    __shared__ float red[128];
    const float* zm = z + (size_t)m * N_NODES * DIM;
    const float* nd = ndst + m * N_NODES;
    const float bj  = b1[tid];
    const float w2j = W2[tid];
    float acc = 0.0f;
    for (int g = blockIdx.x; g < (N_NODES / 8); g += gridDim.x) {
        const int nbase = g * 8;
        float sc[8];
#pragma unroll
        for (int u = 0; u < 8; ++u) sc[u] = nd[nbase + u];
        float q[8] = {0.f, 0.f, 0.f, 0.f, 0.f, 0.f, 0.f, 0.f};
#pragma unroll 4
        for (int d = 0; d < DIM; ++d) {
            const float w1v = W1[d * DIM + tid];
#pragma unroll
            for (int u = 0; u < 8; ++u) {
                const float zr = zm[(size_t)(nbase + u) * DIM + d];
                q[u] = fmaf(zr, w1v, q[u]);
            }
        }
#pragma unroll
        for (int u = 0; u < 8; ++u)
            acc += tanhf(fmaf(q[u], sc[u], bj)) * w2j;
    }
    red[tid] = acc;
    __syncthreads();
    for (int s = 64; s > 0; s >>= 1) {
        if (tid < s) red[tid] += red[tid + s];
        __syncthreads();
    }
    if (tid == 0) atomicAdd(&wacc[m], red[0]);
}

// ---------------------------------------------------------------- epilogue --
__global__ __launch_bounds__(256) void final_kernel(
        const float* __restrict__ z, const float* __restrict__ ndst,
        const float* __restrict__ wacc, float* __restrict__ out) {
    const int g = blockIdx.x * blockDim.x + threadIdx.x;  // float4 index
    if (g >= N_NODES * DIM / 4) return;
    const int n = g >> 5;
    const float invN = 1.0f / (float)N_NODES;
    const float w0 = wacc[0] * invN, w1 = wacc[1] * invN, w2 = wacc[2] * invN;
    const float mx = fmaxf(w0, fmaxf(w1, w2));
    const float e0 = expf(w0 - mx), e1 = expf(w1 - mx), e2 = expf(w2 - mx);
    const float inv = 1.0f / (e0 + e1 + e2);
    const float beta[3] = {e0 * inv, e1 * inv, e2 * inv};
    float4 acc = {0.f, 0.f, 0.f, 0.f};
#pragma unroll
    for (int m = 0; m < N_META; ++m) {
        const float sc = ndst[m * N_NODES + n] * beta[m];
        const float4 zv = *reinterpret_cast<const float4*>(
            z + ((size_t)m * N_NODES) * DIM + (size_t)g * 4);
        acc.x = fmaf(zv.x, sc, acc.x);
        acc.y = fmaf(zv.y, sc, acc.y);
        acc.z = fmaf(zv.z, sc, acc.z);
        acc.w = fmaf(zv.w, sc, acc.w);
    }
    *reinterpret_cast<float4*>(out + (size_t)g * 4) = acc;
}

extern "C" void kernel_launch(void* const* d_in, const int* in_sizes, int n_in,
                              void* d_out, int out_size, void* d_ws, size_t ws_size,
                              hipStream_t stream) {
    const float* h    = (const float*)d_in[0];
    const int*  edges = (const int*)d_in[1];
    const float* W1   = (const float*)d_in[2];
    const float* b1   = (const float*)d_in[3];
    const float* W2   = (const float*)d_in[4];
    float* out = (float*)d_out;

    char* p = (char*)d_ws;
    float* z       = (float*)p;                 p += (size_t)N_META * N_NODES * DIM * 4;
    float* wacc    = (float*)p;                 p += 16 * 4;
    int*   out_cnt = (int*)p;                   p += (size_t)N_META * N_NODES * 4;
    int*   in_cnt  = (int*)p;                   p += (size_t)N_META * N_NODES * 4;
    float* nsrc    = (float*)p;                 p += (size_t)N_META * N_NODES * 4;
    float* ndst    = (float*)p;                 p += (size_t)N_META * N_NODES * 4;
    int*   row_off = (int*)p;                   p += ((size_t)N_META * (N_NODES + 1) + 13) * 4;
    int*   cursor  = (int*)p;                   p += (size_t)N_META * N_NODES * 4;
    int*   csr     = (int*)p;                   p += (size_t)N_META * N_EDGES * 4;

    // zero wacc + both count arrays (contiguous range)
    hipMemsetAsync(wacc, 0, (16 + 2 * (size_t)N_META * N_NODES) * 4, stream);

    deg_kernel <<<dim3(1024, 6), dim3(256), 0, stream>>>(edges, out_cnt, in_cnt);
    norm_kernel<<<dim3((N_META * N_NODES + 255) / 256), dim3(256), 0, stream>>>(
        out_cnt, in_cnt, nsrc, ndst);
    scan_kernel<<<dim3(N_META), dim3(SCAN_T), 0, stream>>>(in_cnt, row_off, cursor);
    fill_kernel<<<dim3(1024, 3), dim3(256), 0, stream>>>(edges, cursor, csr);
    gather_kernel<<<dim3(N_NODES / 4, N_META), dim3(256), 0, stream>>>(
        h, csr, row_off, nsrc, z);
    attn_kernel<<<dim3(625, N_META), dim3(128), 0, stream>>>(z, ndst, W1, b1, W2, wacc);
    final_kernel<<<dim3((N_NODES * DIM / 4 + 255) / 256), dim3(256), 0, stream>>>(
        z, ndst, wacc, out);
}

// Round 3
// 895.054 us; speedup vs baseline: 9.8441x; 1.6896x over previous
//
#include <hip/hip_runtime.h>
#include <cstdint>
#include <cstddef>

#define N_NODES 50000
#define N_EDGES 1600000
#define N_META  3
#define DIM     128

#define BKT_NODES 256                 // dst nodes per bucket
#define NBKT      196                 // ceil(N_NODES / BKT_NODES)
#define BIN_CHUNK 8192                // edges per bin_kernel block
#define NCHUNK    196                 // ceil(N_EDGES / BIN_CHUNK)
#define OCH       16                  // out-degree edge chunks
#define ORANGE    12500               // out-degree node range (x4 ranges)
#define CSR_CAP   10240               // LDS pair stage (mean bucket = 8192, +22 sigma)

// ---------------------------------------------------------------------------
// K1a: per-bucket dst histogram (coarse). LDS-privatized, tiny global flush.
__global__ __launch_bounds__(256) void bucket_hist_kernel(
        const int* __restrict__ edges, int* __restrict__ bucket_cnt) {
    const int m = blockIdx.y;
    __shared__ int hist[NBKT];
    for (int j = threadIdx.x; j < NBKT; j += 256) hist[j] = 0;
    __syncthreads();
    const int* dst = edges + (size_t)(2 * m + 1) * N_EDGES;
    const int beg = blockIdx.x * (N_EDGES / 64);       // 64 blocks x 25000
    for (int i = beg + threadIdx.x; i < beg + (N_EDGES / 64); i += 256)
        atomicAdd(&hist[dst[i] >> 8], 1);
    __syncthreads();
    for (int j = threadIdx.x; j < NBKT; j += 256)
        if (hist[j]) atomicAdd(&bucket_cnt[m * NBKT + j], hist[j]);
}

// ---------------------------------------------------------------------------
// K1b: out-degree via LDS-private sub-range histograms -> non-atomic partials.
__global__ __launch_bounds__(256) void outdeg_kernel(
        const int* __restrict__ edges, int* __restrict__ partials) {
    const int c = blockIdx.x, r = blockIdx.y, m = blockIdx.z;
    __shared__ int h[ORANGE];
    for (int j = threadIdx.x; j < ORANGE; j += 256) h[j] = 0;
    __syncthreads();
    const int* src = edges + (size_t)(2 * m) * N_EDGES;
    const int base = r * ORANGE;
    const int beg = c * (N_EDGES / OCH);
    for (int i = beg + threadIdx.x; i < beg + (N_EDGES / OCH); i += 256) {
        const unsigned u = (unsigned)(src[i] - base);
        if (u < (unsigned)ORANGE) atomicAdd(&h[u], 1);
    }
    __syncthreads();
    int* out = partials + (size_t)(m * OCH + c) * N_NODES + base;
    for (int j = threadIdx.x; j < ORANGE; j += 256) out[j] = h[j];
}

// ---------------------------------------------------------------------------
// K2a: serial scan of 196 bucket counts per metapath (tiny).
__global__ void bucket_scan_kernel(const int* __restrict__ bucket_cnt,
                                   int* __restrict__ bucket_off,
                                   int* __restrict__ bucket_cur,
                                   int* __restrict__ row_off) {
    const int m = blockIdx.x;
    if (threadIdx.x == 0) {
        int acc = 0;
        for (int b = 0; b < NBKT; ++b) {
            bucket_off[m * (NBKT + 1) + b] = acc;
            bucket_cur[m * NBKT + b] = acc;
            acc += bucket_cnt[m * NBKT + b];
        }
        bucket_off[m * (NBKT + 1) + NBKT] = acc;       // == N_EDGES
        row_off[m * (N_NODES + 1) + N_NODES] = N_EDGES;
    }
}

// ---------------------------------------------------------------------------
// K2b: merge out-degree partials -> nsrc = rsqrt(max(deg,1)).
__global__ __launch_bounds__(256) void nsrc_kernel(
        const int* __restrict__ partials, float* __restrict__ nsrc) {
    const int i = blockIdx.x * 256 + threadIdx.x;
    if (i >= N_META * N_NODES) return;
    const int m = i / N_NODES, node = i - m * N_NODES;
    int s = 0;
#pragma unroll
    for (int c = 0; c < OCH; ++c)
        s += partials[(size_t)(m * OCH + c) * N_NODES + node];
    nsrc[i] = rsqrtf(fmaxf((float)s, 1.0f));
}

// ---------------------------------------------------------------------------
// K3: bin edges into dst-buckets. Block-exclusive reservations keep the packed
// pair writes in small single-CU windows (no 64B-line write amplification).
__global__ __launch_bounds__(256) void bin_kernel(
        const int* __restrict__ edges, int* __restrict__ bucket_cur,
        unsigned* __restrict__ pairs) {
    const int m = blockIdx.y;
    __shared__ int hist[NBKT];
    __shared__ int cur[NBKT];
    for (int j = threadIdx.x; j < NBKT; j += 256) hist[j] = 0;
    __syncthreads();
    const int* src = edges + (size_t)(2 * m) * N_EDGES;
    const int* dst = edges + (size_t)(2 * m + 1) * N_EDGES;
    const int beg = blockIdx.x * BIN_CHUNK;
    const int end = min(beg + BIN_CHUNK, N_EDGES);
    for (int i = beg + threadIdx.x; i < end; i += 256)
        atomicAdd(&hist[dst[i] >> 8], 1);
    __syncthreads();
    for (int j = threadIdx.x; j < NBKT; j += 256) {
        const int n = hist[j];
        cur[j] = n ? atomicAdd(&bucket_cur[m * NBKT + j], n) : 0;
    }
    __syncthreads();
    unsigned* pm = pairs + (size_t)m * N_EDGES;
    for (int i = beg + threadIdx.x; i < end; i += 256) {
        const unsigned d = (unsigned)dst[i];
        const int pos = atomicAdd(&cur[d >> 8], 1);
        pm[pos] = (d << 16) | (unsigned)src[i];        // both ids < 65536
    }
}

// ---------------------------------------------------------------------------
// K4: finalize exact CSR per bucket. Scatter window is ~32KB (L2-resident,
// single block) -> clean writebacks. Also emits row_off and ndst.
__global__ __launch_bounds__(256) void csr_kernel(
        const unsigned* __restrict__ pairs, const int* __restrict__ bucket_off,
        int* __restrict__ row_off, float* __restrict__ ndst, int* __restrict__ csr) {
    const int b = blockIdx.x, m = blockIdx.y;
    const int node_base = b * BKT_NODES;
    const int nb = min(BKT_NODES, N_NODES - node_base);
    __shared__ unsigned stage[CSR_CAP];
    __shared__ int hist[BKT_NODES];
    __shared__ int sc[BKT_NODES];
    __shared__ int cur[BKT_NODES];
    hist[threadIdx.x] = 0;
    __syncthreads();
    const int beg = bucket_off[m * (NBKT + 1) + b];
    const int end = bucket_off[m * (NBKT + 1) + b + 1];
    const int cnt = end - beg;
    const unsigned* pm = pairs + (size_t)m * N_EDGES + beg;
    for (int i = threadIdx.x; i < cnt; i += 256) {
        const unsigned p = pm[i];
        if (i < CSR_CAP) stage[i] = p;
        atomicAdd(&hist[(int)(p >> 16) - node_base], 1);
    }
    __syncthreads();
    const int v = hist[threadIdx.x];
    sc[threadIdx.x] = v;
    __syncthreads();
    for (int off = 1; off < BKT_NODES; off <<= 1) {
        const int t = (threadIdx.x >= off) ? sc[threadIdx.x - off] : 0;
        __syncthreads();
        sc[threadIdx.x] += t;
        __syncthreads();
    }
    const int excl = sc[threadIdx.x] - v;
    cur[threadIdx.x] = beg + excl;
    if (threadIdx.x < nb) {
        row_off[m * (N_NODES + 1) + node_base + threadIdx.x] = beg + excl;
        ndst[m * N_NODES + node_base + threadIdx.x] = rsqrtf(fmaxf((float)v, 1.0f));
    }
    __syncthreads();
    int* cm = csr + (size_t)m * N_EDGES;
    for (int i = threadIdx.x; i < cnt; i += 256) {
        const unsigned p = (i < CSR_CAP) ? stage[i] : pm[i];
        const int dl = (int)(p >> 16) - node_base;
        const int pos = atomicAdd(&cur[dl], 1);
        cm[pos] = (int)(p & 0xFFFFu);
    }
}

// ---------------------------------------------------------------------------
// K5: gather. One wave per dst node, lane owns 2 dims, unroll-8 for load ILP.
// z is stored ALREADY ndst-normalized.
__global__ __launch_bounds__(256) void gather_kernel(
        const float* __restrict__ h, const int* __restrict__ csr,
        const int* __restrict__ row_off, const float* __restrict__ nsrc,
        const float* __restrict__ ndst, float* __restrict__ z) {
    const int m    = blockIdx.y;
    const int wave = threadIdx.x >> 6;
    const int lane = threadIdx.x & 63;
    const int node = blockIdx.x * 4 + wave;
    const int* ro = row_off + m * (N_NODES + 1);
    const int beg = ro[node];
    const int end = ro[node + 1];
    const int* srcs = csr + (size_t)m * N_EDGES;
    const float* ns = nsrc + m * N_NODES;
    float2 acc = {0.0f, 0.0f};
    int j = beg;
    for (; j + 8 <= end; j += 8) {
        int s[8];
#pragma unroll
        for (int u = 0; u < 8; ++u) s[u] = srcs[j + u];
        float n[8]; float2 hv[8];
#pragma unroll
        for (int u = 0; u < 8; ++u) {
            n[u] = ns[s[u]];
            hv[u] = *reinterpret_cast<const float2*>(h + (size_t)s[u] * DIM + lane * 2);
        }
#pragma unroll
        for (int u = 0; u < 8; ++u) {
            acc.x = fmaf(hv[u].x, n[u], acc.x);
            acc.y = fmaf(hv[u].y, n[u], acc.y);
        }
    }
    for (; j < end; ++j) {
        const int s0 = srcs[j];
        const float n0 = ns[s0];
        const float2 h0 = *reinterpret_cast<const float2*>(h + (size_t)s0 * DIM + lane * 2);
        acc.x = fmaf(h0.x, n0, acc.x);
        acc.y = fmaf(h0.y, n0, acc.y);
    }
    const float nd = ndst[m * N_NODES + node];
    acc.x *= nd; acc.y *= nd;
    *reinterpret_cast<float2*>(z + ((size_t)m * N_NODES + node) * DIM + lane * 2) = acc;
}

// ---------------------------------------------------------------------------
// K6: semantic attention scores (z already normalized).
__global__ __launch_bounds__(128) void attn_kernel(
        const float* __restrict__ z,
        const float* __restrict__ W1, const float* __restrict__ b1,
        const float* __restrict__ W2, float* __restrict__ wacc) {
    const int m   = blockIdx.y;
    const int tid = threadIdx.x;
    __shared__ float red[128];
    const float* zm = z + (size_t)m * N_NODES * DIM;
    const float bj  = b1[tid];
    const float w2j = W2[tid];
    float acc = 0.0f;
    for (int g = blockIdx.x; g < (N_NODES / 8); g += gridDim.x) {
        const int nbase = g * 8;
        float q[8] = {0.f, 0.f, 0.f, 0.f, 0.f, 0.f, 0.f, 0.f};
#pragma unroll 4
        for (int d = 0; d < DIM; ++d) {
            const float w1v = W1[d * DIM + tid];
#pragma unroll
            for (int u = 0; u < 8; ++u) {
                const float zr = zm[(size_t)(nbase + u) * DIM + d];
                q[u] = fmaf(zr, w1v, q[u]);
            }
        }
#pragma unroll
        for (int u = 0; u < 8; ++u)
            acc += tanhf(q[u] + bj) * w2j;
    }
    red[tid] = acc;
    __syncthreads();
    for (int s = 64; s > 0; s >>= 1) {
        if (tid < s) red[tid] += red[tid + s];
        __syncthreads();
    }
    if (tid == 0) atomicAdd(&wacc[m], red[0]);
}

// ---------------------------------------------------------------------------
// K7: softmax over 3 scores + beta-weighted sum.
__global__ __launch_bounds__(256) void final_kernel(
        const float* __restrict__ z, const float* __restrict__ wacc,
        float* __restrict__ out) {
    const int g = blockIdx.x * 256 + threadIdx.x;      // float4 index
    if (g >= N_NODES * DIM / 4) return;
    const float invN = 1.0f / (float)N_NODES;
    const float w0 = wacc[0] * invN, w1 = wacc[1] * invN, w2 = wacc[2] * invN;
    const float mx = fmaxf(w0, fmaxf(w1, w2));
    const float e0 = expf(w0 - mx), e1 = expf(w1 - mx), e2 = expf(w2 - mx);
    const float inv = 1.0f / (e0 + e1 + e2);
    const float beta[3] = {e0 * inv, e1 * inv, e2 * inv};
    float4 acc = {0.f, 0.f, 0.f, 0.f};
#pragma unroll
    for (int m = 0; m < N_META; ++m) {
        const float4 zv = *reinterpret_cast<const float4*>(
            z + ((size_t)m * N_NODES) * DIM + (size_t)g * 4);
        acc.x = fmaf(zv.x, beta[m], acc.x);
        acc.y = fmaf(zv.y, beta[m], acc.y);
        acc.z = fmaf(zv.z, beta[m], acc.z);
        acc.w = fmaf(zv.w, beta[m], acc.w);
    }
    *reinterpret_cast<float4*>(out + (size_t)g * 4) = acc;
}

extern "C" void kernel_launch(void* const* d_in, const int* in_sizes, int n_in,
                              void* d_out, int out_size, void* d_ws, size_t ws_size,
                              hipStream_t stream) {
    const float* h    = (const float*)d_in[0];
    const int*  edges = (const int*)d_in[1];
    const float* W1   = (const float*)d_in[2];
    const float* b1   = (const float*)d_in[3];
    const float* W2   = (const float*)d_in[4];
    float* out = (float*)d_out;

    // Workspace with lifetime aliasing:
    //   R0 (76.8MB): pairs[19.2MB] + partials[9.6MB] early; z overlays from gather on.
    //   R1 (19.2MB): csr.   misc: wacc|bucket_cnt (memset) | off | cur | row_off | nsrc | ndst
    char* p = (char*)d_ws;
    float*    z        = (float*)p;
    unsigned* pairs    = (unsigned*)p;
    int*      partials = (int*)(p + (size_t)N_META * N_EDGES * 4);
    p += (size_t)N_META * N_NODES * DIM * 4;
    int* csr        = (int*)p;   p += (size_t)N_META * N_EDGES * 4;
    float* wacc     = (float*)p; p += 16 * 4;
    int* bucket_cnt = (int*)p;   p += (size_t)N_META * NBKT * 4;
    int* bucket_off = (int*)p;   p += (size_t)N_META * (NBKT + 1) * 4 + 4;
    int* bucket_cur = (int*)p;   p += (size_t)N_META * NBKT * 4;
    int* row_off    = (int*)p;   p += ((size_t)N_META * (N_NODES + 1) + 1) * 4;
    float* nsrc     = (float*)p; p += (size_t)N_META * N_NODES * 4;
    float* ndst     = (float*)p; p += (size_t)N_META * N_NODES * 4;

    // zero wacc + bucket_cnt (contiguous)
    hipMemsetAsync(wacc, 0, (16 + (size_t)N_META * NBKT) * 4, stream);

    bucket_hist_kernel<<<dim3(64, N_META), 256, 0, stream>>>(edges, bucket_cnt);
    outdeg_kernel<<<dim3(OCH, 4, N_META), 256, 0, stream>>>(edges, partials);
    bucket_scan_kernel<<<dim3(N_META), dim3(64), 0, stream>>>(
        bucket_cnt, bucket_off, bucket_cur, row_off);
    nsrc_kernel<<<dim3((N_META * N_NODES + 255) / 256), 256, 0, stream>>>(partials, nsrc);
    bin_kernel<<<dim3(NCHUNK, N_META), 256, 0, stream>>>(edges, bucket_cur, pairs);
    csr_kernel<<<dim3(NBKT, N_META), 256, 0, stream>>>(pairs, bucket_off, row_off, ndst, csr);
    gather_kernel<<<dim3(N_NODES / 4, N_META), 256, 0, stream>>>(
        h, csr, row_off, nsrc, ndst, z);
    attn_kernel<<<dim3(625, N_META), 128, 0, stream>>>(z, W1, b1, W2, wacc);
    final_kernel<<<dim3((N_NODES * DIM / 4 + 255) / 256), 256, 0, stream>>>(z, wacc, out);
}

// Round 4
// 885.524 us; speedup vs baseline: 9.9501x; 1.0108x over previous
//
#include <hip/hip_runtime.h>
#include <cstdint>
#include <cstddef>

#define N_NODES 50000
#define N_EDGES 1600000
#define N_META  3
#define DIM     128

#define BKT       64                  // dst nodes per bucket
#define NBKT      782                 // ceil(N_NODES / BKT)
#define BIN_CHUNK 16384               // edges per bin block
#define NCHUNK    98                  // ceil(N_EDGES / BIN_CHUNK)
#define OCH       16                  // out-degree edge chunks
#define ORANGE    12500               // out-degree node sub-range (x4)
#define CAP       2816                // LDS pair stage; bucket mean 2048, sigma 45
#define SCAN_T    1024

// ---------------------------------------------------------------------------
// K1a: per-bucket dst histogram. LDS-privatized, tiny global flush.
__global__ __launch_bounds__(256) void bucket_hist_kernel(
        const int* __restrict__ edges, int* __restrict__ bucket_cnt) {
    const int m = blockIdx.y;
    __shared__ int hist[NBKT];
    for (int j = threadIdx.x; j < NBKT; j += 256) hist[j] = 0;
    __syncthreads();
    const int* dst = edges + (size_t)(2 * m + 1) * N_EDGES;
    const int beg = blockIdx.x * (N_EDGES / 64);       // 64 blocks x 25000
    for (int i = beg + threadIdx.x; i < beg + (N_EDGES / 64); i += 256)
        atomicAdd(&hist[dst[i] / BKT], 1);
    __syncthreads();
    for (int j = threadIdx.x; j < NBKT; j += 256)
        if (hist[j]) atomicAdd(&bucket_cnt[m * NBKT + j], hist[j]);
}

// ---------------------------------------------------------------------------
// K1b: out-degree via LDS-private sub-range histograms -> non-atomic partials.
__global__ __launch_bounds__(256) void outdeg_kernel(
        const int* __restrict__ edges, int* __restrict__ partials) {
    const int c = blockIdx.x, r = blockIdx.y, m = blockIdx.z;
    __shared__ int h[ORANGE];
    for (int j = threadIdx.x; j < ORANGE; j += 256) h[j] = 0;
    __syncthreads();
    const int* src = edges + (size_t)(2 * m) * N_EDGES;
    const int base = r * ORANGE;
    const int beg = c * (N_EDGES / OCH);
    for (int i = beg + threadIdx.x; i < beg + (N_EDGES / OCH); i += 256) {
        const unsigned u = (unsigned)(src[i] - base);
        if (u < (unsigned)ORANGE) atomicAdd(&h[u], 1);
    }
    __syncthreads();
    int* out = partials + (size_t)(m * OCH + c) * N_NODES + base;
    for (int j = threadIdx.x; j < ORANGE; j += 256) out[j] = h[j];
}

// ---------------------------------------------------------------------------
// K2a: parallel exclusive scan of 782 bucket counts per metapath.
__global__ __launch_bounds__(SCAN_T) void bucket_scan_kernel(
        const int* __restrict__ bucket_cnt, int* __restrict__ bucket_off,
        int* __restrict__ bucket_cur) {
    const int m = blockIdx.x;
    const int t = threadIdx.x;
    __shared__ int tmp[SCAN_T];
    const int v = (t < NBKT) ? bucket_cnt[m * NBKT + t] : 0;
    tmp[t] = v;
    __syncthreads();
    for (int off = 1; off < SCAN_T; off <<= 1) {
        const int x = (t >= off) ? tmp[t - off] : 0;
        __syncthreads();
        tmp[t] += x;
        __syncthreads();
    }
    if (t < NBKT) {
        bucket_off[m * (NBKT + 1) + t] = tmp[t] - v;
        bucket_cur[m * NBKT + t] = tmp[t] - v;
    }
    if (t == SCAN_T - 1) bucket_off[m * (NBKT + 1) + NBKT] = tmp[t];  // == E
}

// ---------------------------------------------------------------------------
// K2b: merge out-degree partials -> nsrc = rsqrt(max(deg,1)).
__global__ __launch_bounds__(256) void nsrc_kernel(
        const int* __restrict__ partials, float* __restrict__ nsrc) {
    const int i = blockIdx.x * 256 + threadIdx.x;
    if (i >= N_META * N_NODES) return;
    const int m = i / N_NODES, node = i - m * N_NODES;
    int s = 0;
#pragma unroll
    for (int c = 0; c < OCH; ++c)
        s += partials[(size_t)(m * OCH + c) * N_NODES + node];
    nsrc[i] = rsqrtf(fmaxf((float)s, 1.0f));
}

// ---------------------------------------------------------------------------
// K3: bin edges into dst-buckets as packed (dst<<16|src) pairs. Block-exclusive
// window reservations keep writes in small coalesced regions.
__global__ __launch_bounds__(256) void bin_kernel(
        const int* __restrict__ edges, int* __restrict__ bucket_cur,
        unsigned* __restrict__ pairs) {
    const int m = blockIdx.y;
    __shared__ int hist[NBKT];
    __shared__ int cur[NBKT];
    for (int j = threadIdx.x; j < NBKT; j += 256) hist[j] = 0;
    __syncthreads();
    const int* src = edges + (size_t)(2 * m) * N_EDGES;
    const int* dst = edges + (size_t)(2 * m + 1) * N_EDGES;
    const int beg = blockIdx.x * BIN_CHUNK;
    const int end = min(beg + BIN_CHUNK, N_EDGES);
    for (int i = beg + threadIdx.x; i < end; i += 256)
        atomicAdd(&hist[dst[i] / BKT], 1);
    __syncthreads();
    for (int j = threadIdx.x; j < NBKT; j += 256) {
        const int n = hist[j];
        cur[j] = n ? atomicAdd(&bucket_cur[m * NBKT + j], n) : 0;
    }
    __syncthreads();
    unsigned* pm = pairs + (size_t)m * N_EDGES;
    for (int i = beg + threadIdx.x; i < end; i += 256) {
        const unsigned d = (unsigned)dst[i];
        const int pos = atomicAdd(&cur[d / BKT], 1);
        pm[pos] = (d << 16) | (unsigned)src[i];        // both ids < 65536
    }
}

// ---------------------------------------------------------------------------
// K4: FUSED csr-sort + gather + semantic attention.
//  - stage bucket pairs in LDS, 64-bin count/scan/place -> per-node src lists
//  - wave w accumulates nodes [16w,16w+16): register float2 acc per lane,
//    coalesced 512B h-row reads, ndst from in-LDS degree (free)
//  - z rows parked in LDS (zbuf), attn tanh(z@W1+b)@W2 with W1 amortized x16
__global__ __launch_bounds__(256, 3) void fused_gather_attn(
        const float* __restrict__ h, const unsigned* __restrict__ pairs,
        const int* __restrict__ bucket_off, const float* __restrict__ nsrc,
        const float* __restrict__ W1, const float* __restrict__ b1,
        const float* __restrict__ W2, float* __restrict__ z,
        float* __restrict__ wacc) {
    const int m = blockIdx.y, b = blockIdx.x;
    const int tid = threadIdx.x;
    const int w = tid >> 6, lane = tid & 63;
    const int node_base = b * BKT;
    const int nb = min(BKT, N_NODES - node_base);

    __shared__ unsigned stage[CAP];
    __shared__ unsigned short sorted[CAP];
    __shared__ int hist[BKT];
    __shared__ int tmp[BKT];
    __shared__ int cur[BKT];
    __shared__ int rs[BKT + 1];
    __shared__ __align__(16) float zbuf[4][16][DIM];

    if (tid < BKT) hist[tid] = 0;
    __syncthreads();

    const int beg = bucket_off[m * (NBKT + 1) + b];
    const int end = bucket_off[m * (NBKT + 1) + b + 1];
    int cnt = end - beg;
    if (cnt > CAP) cnt = CAP;  // statistically impossible; protects LDS
    const unsigned* pm = pairs + (size_t)m * N_EDGES + beg;
    for (int i = tid; i < cnt; i += 256) {
        const unsigned p = pm[i];
        stage[i] = p;
        atomicAdd(&hist[(int)(p >> 16) - node_base], 1);
    }
    __syncthreads();
    // exclusive scan over 64 bins
    int v = 0;
    if (tid < BKT) { v = hist[tid]; tmp[tid] = v; }
    __syncthreads();
    for (int off = 1; off < BKT; off <<= 1) {
        int t = 0;
        if (tid < BKT && tid >= off) t = tmp[tid - off];
        __syncthreads();
        if (tid < BKT) tmp[tid] += t;
        __syncthreads();
    }
    if (tid < BKT) {
        rs[tid]  = tmp[tid] - v;
        cur[tid] = tmp[tid] - v;
    }
    if (tid == 0) rs[BKT] = cnt;
    __syncthreads();
    // place: per-node grouped src lists (16-bit ids)
    for (int i = tid; i < cnt; i += 256) {
        const unsigned p = stage[i];
        const int d = (int)(p >> 16) - node_base;
        const int pos = atomicAdd(&cur[d], 1);
        sorted[pos] = (unsigned short)(p & 0xFFFFu);
    }
    __syncthreads();

    const float* ns = nsrc + m * N_NODES;
    const int kn = min(16, nb - w * 16);
    float lacc = 0.0f;
    if (kn > 0) {
        for (int k = 0; k < kn; ++k) {
            const int nl = w * 16 + k;
            const int jb = rs[nl], je = rs[nl + 1];
            float2 acc = {0.0f, 0.0f};
            int j = jb;
            for (; j + 8 <= je; j += 8) {
                int s[8]; float n[8]; float2 hv[8];
#pragma unroll
                for (int u = 0; u < 8; ++u) s[u] = sorted[j + u];
#pragma unroll
                for (int u = 0; u < 8; ++u) {
                    n[u]  = ns[s[u]];
                    hv[u] = *reinterpret_cast<const float2*>(h + (size_t)s[u] * DIM + lane * 2);
                }
#pragma unroll
                for (int u = 0; u < 8; ++u) {
                    acc.x = fmaf(hv[u].x, n[u], acc.x);
                    acc.y = fmaf(hv[u].y, n[u], acc.y);
                }
            }
            for (; j < je; ++j) {
                const int s0 = sorted[j];
                const float n0 = ns[s0];
                const float2 h0 = *reinterpret_cast<const float2*>(h + (size_t)s0 * DIM + lane * 2);
                acc.x = fmaf(h0.x, n0, acc.x);
                acc.y = fmaf(h0.y, n0, acc.y);
            }
            const float nd = rsqrtf(fmaxf((float)(je - jb), 1.0f));
            acc.x *= nd; acc.y *= nd;
            *reinterpret_cast<float2*>(&zbuf[w][k][lane * 2]) = acc;
            *reinterpret_cast<float2*>(
                z + ((size_t)m * N_NODES + node_base + nl) * DIM + lane * 2) = acc;
        }
        // attention: lane owns output cols {2*lane, 2*lane+1}; W1 amortized over kn nodes
        float2 q[16];
#pragma unroll
        for (int k = 0; k < 16; ++k) q[k] = make_float2(0.0f, 0.0f);
        for (int d = 0; d < DIM; d += 4) {
            float2 w1v[4];
#pragma unroll
            for (int i = 0; i < 4; ++i)
                w1v[i] = *reinterpret_cast<const float2*>(W1 + (size_t)(d + i) * DIM + lane * 2);
#pragma unroll
            for (int k = 0; k < 16; ++k) {
                if (k < kn) {
                    const float4 zd = *reinterpret_cast<const float4*>(&zbuf[w][k][d]);
                    q[k].x += zd.x * w1v[0].x + zd.y * w1v[1].x + zd.z * w1v[2].x + zd.w * w1v[3].x;
                    q[k].y += zd.x * w1v[0].y + zd.y * w1v[1].y + zd.z * w1v[2].y + zd.w * w1v[3].y;
                }
            }
        }
        const float2 bb = *reinterpret_cast<const float2*>(b1 + lane * 2);
        const float2 ww = *reinterpret_cast<const float2*>(W2 + lane * 2);
#pragma unroll
        for (int k = 0; k < 16; ++k)
            if (k < kn)
                lacc += tanhf(q[k].x + bb.x) * ww.x + tanhf(q[k].y + bb.y) * ww.y;
    }
    for (int off = 32; off > 0; off >>= 1)
        lacc += __shfl_xor(lacc, off);
    if (lane == 0) atomicAdd(&wacc[m], lacc);
}

// ---------------------------------------------------------------------------
// K5: softmax over 3 scores + beta-weighted sum.
__global__ __launch_bounds__(256) void final_kernel(
        const float* __restrict__ z, const float* __restrict__ wacc,
        float* __restrict__ out) {
    const int g = blockIdx.x * 256 + threadIdx.x;      // float4 index
    if (g >= N_NODES * DIM / 4) return;
    const float invN = 1.0f / (float)N_NODES;
    const float w0 = wacc[0] * invN, w1 = wacc[1] * invN, w2 = wacc[2] * invN;
    const float mx = fmaxf(w0, fmaxf(w1, w2));
    const float e0 = expf(w0 - mx), e1 = expf(w1 - mx), e2 = expf(w2 - mx);
    const float inv = 1.0f / (e0 + e1 + e2);
    const float beta[3] = {e0 * inv, e1 * inv, e2 * inv};
    float4 acc = {0.f, 0.f, 0.f, 0.f};
#pragma unroll
    for (int m = 0; m < N_META; ++m) {
        const float4 zv = *reinterpret_cast<const float4*>(
            z + ((size_t)m * N_NODES) * DIM + (size_t)g * 4);
        acc.x = fmaf(zv.x, beta[m], acc.x);
        acc.y = fmaf(zv.y, beta[m], acc.y);
        acc.z = fmaf(zv.z, beta[m], acc.z);
        acc.w = fmaf(zv.w, beta[m], acc.w);
    }
    *reinterpret_cast<float4*>(out + (size_t)g * 4) = acc;
}

extern "C" void kernel_launch(void* const* d_in, const int* in_sizes, int n_in,
                              void* d_out, int out_size, void* d_ws, size_t ws_size,
                              hipStream_t stream) {
    const float* h    = (const float*)d_in[0];
    const int*  edges = (const int*)d_in[1];
    const float* W1   = (const float*)d_in[2];
    const float* b1   = (const float*)d_in[3];
    const float* W2   = (const float*)d_in[4];
    float* out = (float*)d_out;

    // ws layout (~96.6MB): z[76.8MB] (partials[9.6MB] aliases its head — dead
    // before z is written) | pairs[19.2MB] | wacc | bucket_cnt | off | cur | nsrc
    char* p = (char*)d_ws;
    float*    z        = (float*)p;
    int*      partials = (int*)p;
    p += (size_t)N_META * N_NODES * DIM * 4;
    unsigned* pairs    = (unsigned*)p; p += (size_t)N_META * N_EDGES * 4;
    float* wacc        = (float*)p;    p += 16 * 4;
    int* bucket_cnt    = (int*)p;      p += (size_t)N_META * NBKT * 4;
    int* bucket_off    = (int*)p;      p += (size_t)N_META * (NBKT + 1) * 4 + 4;
    int* bucket_cur    = (int*)p;      p += (size_t)N_META * NBKT * 4;
    float* nsrc        = (float*)p;    p += (size_t)N_META * N_NODES * 4;

    // zero wacc + bucket_cnt (contiguous)
    hipMemsetAsync(wacc, 0, (16 + (size_t)N_META * NBKT) * 4, stream);

    bucket_hist_kernel<<<dim3(64, N_META), 256, 0, stream>>>(edges, bucket_cnt);
    outdeg_kernel<<<dim3(OCH, 4, N_META), 256, 0, stream>>>(edges, partials);
    bucket_scan_kernel<<<dim3(N_META), dim3(SCAN_T), 0, stream>>>(
        bucket_cnt, bucket_off, bucket_cur);
    nsrc_kernel<<<dim3((N_META * N_NODES + 255) / 256), 256, 0, stream>>>(partials, nsrc);
    bin_kernel<<<dim3(NCHUNK, N_META), 256, 0, stream>>>(edges, bucket_cur, pairs);
    fused_gather_attn<<<dim3(NBKT, N_META), 256, 0, stream>>>(
        h, pairs, bucket_off, nsrc, W1, b1, W2, z, wacc);
    final_kernel<<<dim3((N_NODES * DIM / 4 + 255) / 256), 256, 0, stream>>>(z, wacc, out);
}

// Round 5
// 731.257 us; speedup vs baseline: 12.0492x; 1.2110x over previous
//
#include <hip/hip_runtime.h>
#include <cstdint>
#include <cstddef>

typedef unsigned int  uint;
typedef unsigned short ushort;

#define N_NODES 50000
#define N_EDGES 1600000
#define N_META  3
#define DIM     128

#define BKT       256                 // dst nodes per bucket
#define NBKT      196                 // ceil(N_NODES / BKT)
#define BIN_CHUNK 16384
#define NCHUNK    98                  // ceil(N_EDGES / BIN_CHUNK)
#define CSR_CAP   10240               // bucket mean 8192, +22 sigma
#define CONV_B    160                 // prep role block ranges
#define HIST_B    192                 // 64 per metapath
#define ODEG_B    48                  // 16 per metapath
#define OCH       16                  // out-degree edge chunks
#define OWORDS    12500               // 50000 nodes / 4 per uint (byte-packed)

__device__ __forceinline__ uint bf16rne(float f) {
    const uint u = __float_as_uint(f);
    return (u + 0x7FFFu + ((u >> 16) & 1u)) >> 16;
}
__device__ __forceinline__ float bflo(uint p) { return __uint_as_float(p << 16); }
__device__ __forceinline__ float bfhi(uint p) { return __uint_as_float(p & 0xFFFF0000u); }

// ---------------------------------------------------------------------------
// K1: merged prep — role by block range.
//   [0,CONV_B)      : h fp32 -> hb bf16
//   [.., +HIST_B)   : per-bucket dst histogram (LDS, flush to bucket_cnt)
//   [.., +ODEG_B)   : out-degree, byte-packed LDS histogram (4 nodes/uint),
//                     per-chunk counts <= ~15 so bytes never overflow
__global__ __launch_bounds__(256) void prep_kernel(
        const float* __restrict__ h, const int* __restrict__ edges,
        ushort* __restrict__ hb, int* __restrict__ bucket_cnt,
        uint* __restrict__ partials) {
    __shared__ uint sh[OWORDS];
    const int blk = blockIdx.x;
    if (blk < CONV_B) {
        const int total = N_NODES * DIM / 4;
        for (int i = blk * 256 + threadIdx.x; i < total; i += CONV_B * 256) {
            const float4 v = reinterpret_cast<const float4*>(h)[i];
            uint2 o;
            o.x = bf16rne(v.x) | (bf16rne(v.y) << 16);
            o.y = bf16rne(v.z) | (bf16rne(v.w) << 16);
            reinterpret_cast<uint2*>(hb)[i] = o;
        }
    } else if (blk < CONV_B + HIST_B) {
        const int b2 = blk - CONV_B;
        const int m = b2 >> 6, c = b2 & 63;
        for (int j = threadIdx.x; j < NBKT; j += 256) sh[j] = 0;
        __syncthreads();
        const int* dst = edges + (size_t)(2 * m + 1) * N_EDGES;
        const int beg = c * (N_EDGES / 64);
        for (int i = beg + threadIdx.x; i < beg + (N_EDGES / 64); i += 256)
            atomicAdd(&sh[dst[i] >> 8], 1u);
        __syncthreads();
        for (int j = threadIdx.x; j < NBKT; j += 256)
            if (sh[j]) atomicAdd(&bucket_cnt[m * NBKT + j], (int)sh[j]);
    } else {
        const int b3 = blk - CONV_B - HIST_B;
        const int m = b3 >> 4, c = b3 & 15;
        for (int j = threadIdx.x; j < OWORDS; j += 256) sh[j] = 0;
        __syncthreads();
        const int* src = edges + (size_t)(2 * m) * N_EDGES;
        const int beg = c * (N_EDGES / OCH);
        for (int i = beg + threadIdx.x; i < beg + (N_EDGES / OCH); i += 256) {
            const int s = src[i];
            atomicAdd(&sh[s >> 2], 1u << (8 * (s & 3)));
        }
        __syncthreads();
        uint* out = partials + (size_t)(m * OCH + c) * OWORDS;
        for (int j = threadIdx.x; j < OWORDS; j += 256) out[j] = sh[j];
    }
}

// ---------------------------------------------------------------------------
// K2: merged bucket scan (3 blocks, serial over 196) + nsrc merge (147 blocks).
__global__ __launch_bounds__(1024) void scan_nsrc_kernel(
        const int* __restrict__ bucket_cnt, int* __restrict__ bucket_off,
        int* __restrict__ bucket_cur, int* __restrict__ row_off,
        const uint* __restrict__ partials, float* __restrict__ nsrc) {
    const int blk = blockIdx.x;
    if (blk < N_META) {
        if (threadIdx.x == 0) {
            const int m = blk;
            int acc = 0;
            for (int b = 0; b < NBKT; ++b) {
                bucket_off[m * (NBKT + 1) + b] = acc;
                bucket_cur[m * NBKT + b] = acc;
                acc += bucket_cnt[m * NBKT + b];
            }
            bucket_off[m * (NBKT + 1) + NBKT] = acc;      // == N_EDGES
            row_off[m * (N_NODES + 1) + N_NODES] = N_EDGES;
        }
    } else {
        const int i = (blk - N_META) * 1024 + threadIdx.x;
        if (i < N_META * N_NODES) {
            const int m = i / N_NODES, node = i - m * N_NODES;
            const int q = node >> 2, s8 = 8 * (node & 3);
            int s = 0;
#pragma unroll
            for (int c = 0; c < OCH; ++c)
                s += (partials[(size_t)(m * OCH + c) * OWORDS + q] >> s8) & 0xFF;
            nsrc[i] = rsqrtf(fmaxf((float)s, 1.0f));
        }
    }
}

// ---------------------------------------------------------------------------
// K3: bin edges into dst-buckets as packed (dst<<16|src) pairs; block-exclusive
// window reservations (windows ~84 edges -> write amp ~1.25x).
__global__ __launch_bounds__(256) void bin_kernel(
        const int* __restrict__ edges, int* __restrict__ bucket_cur,
        uint* __restrict__ pairs) {
    const int m = blockIdx.y;
    __shared__ int hist[NBKT];
    __shared__ int cur[NBKT];
    for (int j = threadIdx.x; j < NBKT; j += 256) hist[j] = 0;
    __syncthreads();
    const int* src = edges + (size_t)(2 * m) * N_EDGES;
    const int* dst = edges + (size_t)(2 * m + 1) * N_EDGES;
    const int beg = blockIdx.x * BIN_CHUNK;
    const int end = min(beg + BIN_CHUNK, N_EDGES);
    for (int i = beg + threadIdx.x; i < end; i += 256)
        atomicAdd(&hist[dst[i] >> 8], 1);
    __syncthreads();
    for (int j = threadIdx.x; j < NBKT; j += 256) {
        const int n = hist[j];
        cur[j] = n ? atomicAdd(&bucket_cur[m * NBKT + j], n) : 0;
    }
    __syncthreads();
    uint* pm = pairs + (size_t)m * N_EDGES;
    for (int i = beg + threadIdx.x; i < end; i += 256) {
        const uint d = (uint)dst[i];
        const int pos = atomicAdd(&cur[d >> 8], 1);
        pm[pos] = (d << 16) | (uint)src[i];
    }
}

// ---------------------------------------------------------------------------
// K4: finalize CSR per bucket (ushort src ids; 16KB scatter window, L2-clean).
__global__ __launch_bounds__(256) void csr_kernel(
        const uint* __restrict__ pairs, const int* __restrict__ bucket_off,
        int* __restrict__ row_off, ushort* __restrict__ csr) {
    const int b = blockIdx.x, m = blockIdx.y;
    const int node_base = b * BKT;
    const int nb = min(BKT, N_NODES - node_base);
    __shared__ uint stage[CSR_CAP];
    __shared__ int hist[BKT];
    __shared__ int sc[BKT];
    __shared__ int cur[BKT];
    hist[threadIdx.x] = 0;
    __syncthreads();
    const int beg = bucket_off[m * (NBKT + 1) + b];
    const int end = bucket_off[m * (NBKT + 1) + b + 1];
    const int cnt = end - beg;
    const uint* pm = pairs + (size_t)m * N_EDGES + beg;
    for (int i = threadIdx.x; i < cnt; i += 256) {
        const uint p = pm[i];
        if (i < CSR_CAP) stage[i] = p;
        atomicAdd(&hist[(int)(p >> 16) - node_base], 1);
    }
    __syncthreads();
    const int v = hist[threadIdx.x];
    sc[threadIdx.x] = v;
    __syncthreads();
    for (int off = 1; off < BKT; off <<= 1) {
        const int t = (threadIdx.x >= off) ? sc[threadIdx.x - off] : 0;
        __syncthreads();
        sc[threadIdx.x] += t;
        __syncthreads();
    }
    const int excl = sc[threadIdx.x] - v;
    cur[threadIdx.x] = beg + excl;
    if (threadIdx.x < nb)
        row_off[m * (N_NODES + 1) + node_base + threadIdx.x] = beg + excl;
    __syncthreads();
    ushort* cm = csr + (size_t)m * N_EDGES;
    for (int i = threadIdx.x; i < cnt; i += 256) {
        const uint p = (i < CSR_CAP) ? stage[i] : pm[i];
        const int dl = (int)(p >> 16) - node_base;
        const int pos = atomicAdd(&cur[dl], 1);
        cm[pos] = (ushort)(p & 0xFFFFu);
    }
}

// ---------------------------------------------------------------------------
// K5: gather (bf16 h). One wave per dst node; HALF-wave covers a full 256B
// bf16 row (32 lanes x 8B = 4 dims/lane), so a wave runs 2 edges/step,
// unroll-8 -> 16 edges in flight. Halves merged by one shfl_xor(32).
__global__ __launch_bounds__(256) void gather_kernel(
        const ushort* __restrict__ hb, const ushort* __restrict__ csr,
        const int* __restrict__ row_off, const float* __restrict__ nsrc,
        float* __restrict__ z) {
    const int m    = blockIdx.y;
    const int wave = threadIdx.x >> 6;
    const int lane = threadIdx.x & 63;
    const int half = lane >> 5;
    const int c    = lane & 31;              // dims 4c..4c+3
    const int node = blockIdx.x * 4 + wave;
    const int* ro = row_off + m * (N_NODES + 1);
    const int beg = ro[node];
    const int end = ro[node + 1];
    const ushort* srcs = csr + (size_t)m * N_EDGES;
    const float* ns = nsrc + m * N_NODES;
    float4 acc = {0.f, 0.f, 0.f, 0.f};
    int j = beg;
    for (; j + 16 <= end; j += 16) {
        int s[8]; float n[8]; uint2 hv[8];
#pragma unroll
        for (int u = 0; u < 8; ++u) s[u] = srcs[j + 2 * u + half];
#pragma unroll
        for (int u = 0; u < 8; ++u) {
            n[u]  = ns[s[u]];
            hv[u] = *reinterpret_cast<const uint2*>(hb + (size_t)s[u] * DIM + c * 4);
        }
#pragma unroll
        for (int u = 0; u < 8; ++u) {
            acc.x = fmaf(bflo(hv[u].x), n[u], acc.x);
            acc.y = fmaf(bfhi(hv[u].x), n[u], acc.y);
            acc.z = fmaf(bflo(hv[u].y), n[u], acc.z);
            acc.w = fmaf(bfhi(hv[u].y), n[u], acc.w);
        }
    }
    for (; j + 2 <= end; j += 2) {
        const int s0 = srcs[j + half];
        const float n0 = ns[s0];
        const uint2 h0 = *reinterpret_cast<const uint2*>(hb + (size_t)s0 * DIM + c * 4);
        acc.x = fmaf(bflo(h0.x), n0, acc.x);
        acc.y = fmaf(bfhi(h0.x), n0, acc.y);
        acc.z = fmaf(bflo(h0.y), n0, acc.z);
        acc.w = fmaf(bfhi(h0.y), n0, acc.w);
    }
    if (j < end && half == 0) {
        const int s0 = srcs[j];
        const float n0 = ns[s0];
        const uint2 h0 = *reinterpret_cast<const uint2*>(hb + (size_t)s0 * DIM + c * 4);
        acc.x = fmaf(bflo(h0.x), n0, acc.x);
        acc.y = fmaf(bfhi(h0.x), n0, acc.y);
        acc.z = fmaf(bflo(h0.y), n0, acc.z);
        acc.w = fmaf(bfhi(h0.y), n0, acc.w);
    }
    acc.x += __shfl_xor(acc.x, 32);
    acc.y += __shfl_xor(acc.y, 32);
    acc.z += __shfl_xor(acc.z, 32);
    acc.w += __shfl_xor(acc.w, 32);
    if (half == 0) {
        const float nd = rsqrtf(fmaxf((float)(end - beg), 1.0f));
        float4 o;
        o.x = acc.x * nd; o.y = acc.y * nd; o.z = acc.z * nd; o.w = acc.w * nd;
        *reinterpret_cast<float4*>(
            z + ((size_t)m * N_NODES + node) * DIM + c * 4) = o;
    }
}

// ---------------------------------------------------------------------------
// K6: semantic attention scores (z already ndst-normalized).
__global__ __launch_bounds__(128) void attn_kernel(
        const float* __restrict__ z,
        const float* __restrict__ W1, const float* __restrict__ b1,
        const float* __restrict__ W2, float* __restrict__ wacc) {
    const int m   = blockIdx.y;
    const int tid = threadIdx.x;
    __shared__ float red[128];
    const float* zm = z + (size_t)m * N_NODES * DIM;
    const float bj  = b1[tid];
    const float w2j = W2[tid];
    float acc = 0.0f;
    for (int g = blockIdx.x; g < (N_NODES / 8); g += gridDim.x) {
        const int nbase = g * 8;
        float q[8] = {0.f, 0.f, 0.f, 0.f, 0.f, 0.f, 0.f, 0.f};
#pragma unroll 4
        for (int d = 0; d < DIM; ++d) {
            const float w1v = W1[d * DIM + tid];
#pragma unroll
            for (int u = 0; u < 8; ++u) {
                const float zr = zm[(size_t)(nbase + u) * DIM + d];
                q[u] = fmaf(zr, w1v, q[u]);
            }
        }
#pragma unroll
        for (int u = 0; u < 8; ++u)
            acc += tanhf(q[u] + bj) * w2j;
    }
    red[tid] = acc;
    __syncthreads();
    for (int s = 64; s > 0; s >>= 1) {
        if (tid < s) red[tid] += red[tid + s];
        __syncthreads();
    }
    if (tid == 0) atomicAdd(&wacc[m], red[0]);
}

// ---------------------------------------------------------------------------
// K7: softmax over 3 scores + beta-weighted sum.
__global__ __launch_bounds__(256) void final_kernel(
        const float* __restrict__ z, const float* __restrict__ wacc,
        float* __restrict__ out) {
    const int g = blockIdx.x * 256 + threadIdx.x;      // float4 index
    if (g >= N_NODES * DIM / 4) return;
    const float invN = 1.0f / (float)N_NODES;
    const float w0 = wacc[0] * invN, w1 = wacc[1] * invN, w2 = wacc[2] * invN;
    const float mx = fmaxf(w0, fmaxf(w1, w2));
    const float e0 = expf(w0 - mx), e1 = expf(w1 - mx), e2 = expf(w2 - mx);
    const float inv = 1.0f / (e0 + e1 + e2);
    const float beta[3] = {e0 * inv, e1 * inv, e2 * inv};
    float4 acc = {0.f, 0.f, 0.f, 0.f};
#pragma unroll
    for (int m = 0; m < N_META; ++m) {
        const float4 zv = *reinterpret_cast<const float4*>(
            z + ((size_t)m * N_NODES) * DIM + (size_t)g * 4);
        acc.x = fmaf(zv.x, beta[m], acc.x);
        acc.y = fmaf(zv.y, beta[m], acc.y);
        acc.z = fmaf(zv.z, beta[m], acc.z);
        acc.w = fmaf(zv.w, beta[m], acc.w);
    }
    *reinterpret_cast<float4*>(out + (size_t)g * 4) = acc;
}

extern "C" void kernel_launch(void* const* d_in, const int* in_sizes, int n_in,
                              void* d_out, int out_size, void* d_ws, size_t ws_size,
                              hipStream_t stream) {
    const float* h    = (const float*)d_in[0];
    const int*  edges = (const int*)d_in[1];
    const float* W1   = (const float*)d_in[2];
    const float* b1   = (const float*)d_in[3];
    const float* W2   = (const float*)d_in[4];
    float* out = (float*)d_out;

    // ws (~100MB): z[76.8MB] region hosts pairs[19.2MB]+partials[2.4MB] early
    // (both dead before gather writes z) | hb | csr | row_off | nsrc | small
    char* p = (char*)d_ws;
    float* z        = (float*)p;
    uint*  pairs    = (uint*)p;
    uint*  partials = (uint*)(p + (size_t)N_META * N_EDGES * 4);
    p += (size_t)N_META * N_NODES * DIM * 4;
    ushort* hb      = (ushort*)p; p += (size_t)N_NODES * DIM * 2;
    ushort* csr     = (ushort*)p; p += (size_t)N_META * N_EDGES * 2;
    int* row_off    = (int*)p;    p += ((size_t)N_META * (N_NODES + 1) + 1) * 4;
    float* nsrc     = (float*)p;  p += (size_t)N_META * N_NODES * 4;
    float* wacc     = (float*)p;  p += 16 * 4;
    int* bucket_cnt = (int*)p;    p += (size_t)N_META * NBKT * 4;
    int* bucket_off = (int*)p;    p += (size_t)N_META * (NBKT + 1) * 4 + 4;
    int* bucket_cur = (int*)p;    p += (size_t)N_META * NBKT * 4;

    // zero wacc + bucket_cnt (contiguous)
    hipMemsetAsync(wacc, 0, (16 + (size_t)N_META * NBKT) * 4, stream);

    prep_kernel<<<dim3(CONV_B + HIST_B + ODEG_B), 256, 0, stream>>>(
        h, edges, hb, bucket_cnt, partials);
    scan_nsrc_kernel<<<dim3(N_META + (N_META * N_NODES + 1023) / 1024), 1024, 0, stream>>>(
        bucket_cnt, bucket_off, bucket_cur, row_off, partials, nsrc);
    bin_kernel<<<dim3(NCHUNK, N_META), 256, 0, stream>>>(edges, bucket_cur, pairs);
    csr_kernel<<<dim3(NBKT, N_META), 256, 0, stream>>>(pairs, bucket_off, row_off, csr);
    gather_kernel<<<dim3(N_NODES / 4, N_META), 256, 0, stream>>>(
        hb, csr, row_off, nsrc, z);
    attn_kernel<<<dim3(625, N_META), 128, 0, stream>>>(z, W1, b1, W2, wacc);
    final_kernel<<<dim3((N_NODES * DIM / 4 + 255) / 256), 256, 0, stream>>>(z, wacc, out);
}

// Round 6
// 623.337 us; speedup vs baseline: 14.1353x; 1.1731x over previous
//
#include <hip/hip_runtime.h>
#include <cstdint>
#include <cstddef>

typedef unsigned int  uint;
typedef unsigned short ushort;

#define N_NODES 50000
#define N_EDGES 1600000
#define N_META  3
#define DIM     128

#define BKT       256                 // dst nodes per bucket
#define NBKT      196                 // ceil(N_NODES / BKT)
#define BIN_CHUNK 16384
#define NCHUNK    98                  // ceil(N_EDGES / BIN_CHUNK)
#define CSR_CAP   10240               // bucket mean 8192, +22 sigma
#define CONV_B    160                 // prep role block ranges
#define HIST_B    192                 // 64 per metapath
#define ODEG_B    48                  // 16 per metapath
#define W1C_B     4                   // W1 fp32 -> bf16
#define OCH       16                  // out-degree edge chunks
#define OWORDS    12500               // 50000 nodes / 4 per uint (byte-packed)

#define AT_TILE   64                  // attn: nodes per block
#define AT_NBLK   782                 // ceil(N_NODES / AT_TILE)
#define ZSTR      72                  // zT row stride (ushorts), 16B-aligned rows

__device__ __forceinline__ uint bf16rne(float f) {
    const uint u = __float_as_uint(f);
    return (u + 0x7FFFu + ((u >> 16) & 1u)) >> 16;
}
__device__ __forceinline__ float bflo(uint p) { return __uint_as_float(p << 16); }
__device__ __forceinline__ float bfhi(uint p) { return __uint_as_float(p & 0xFFFF0000u); }

// ---------------------------------------------------------------------------
// K1: merged prep — role by block range.
//   [0,CONV_B)    : h fp32 -> hb bf16
//   [..,+HIST_B)  : per-bucket dst histogram (LDS, flush to bucket_cnt)
//   [..,+ODEG_B)  : out-degree, byte-packed LDS histogram (4 nodes/uint)
//   [..,+W1C_B)   : W1 fp32 -> bf16
__global__ __launch_bounds__(256) void prep_kernel(
        const float* __restrict__ h, const int* __restrict__ edges,
        const float* __restrict__ W1, ushort* __restrict__ hb,
        int* __restrict__ bucket_cnt, uint* __restrict__ partials,
        ushort* __restrict__ W1b) {
    __shared__ uint sh[OWORDS];
    const int blk = blockIdx.x;
    if (blk < CONV_B) {
        const int total = N_NODES * DIM / 4;
        for (int i = blk * 256 + threadIdx.x; i < total; i += CONV_B * 256) {
            const float4 v = reinterpret_cast<const float4*>(h)[i];
            uint2 o;
            o.x = bf16rne(v.x) | (bf16rne(v.y) << 16);
            o.y = bf16rne(v.z) | (bf16rne(v.w) << 16);
            reinterpret_cast<uint2*>(hb)[i] = o;
        }
    } else if (blk < CONV_B + HIST_B) {
        const int b2 = blk - CONV_B;
        const int m = b2 >> 6, c = b2 & 63;
        for (int j = threadIdx.x; j < NBKT; j += 256) sh[j] = 0;
        __syncthreads();
        const int* dst = edges + (size_t)(2 * m + 1) * N_EDGES;
        const int beg = c * (N_EDGES / 64);
        for (int i = beg + threadIdx.x; i < beg + (N_EDGES / 64); i += 256)
            atomicAdd(&sh[dst[i] >> 8], 1u);
        __syncthreads();
        for (int j = threadIdx.x; j < NBKT; j += 256)
            if (sh[j]) atomicAdd(&bucket_cnt[m * NBKT + j], (int)sh[j]);
    } else if (blk < CONV_B + HIST_B + ODEG_B) {
        const int b3 = blk - CONV_B - HIST_B;
        const int m = b3 >> 4, c = b3 & 15;
        for (int j = threadIdx.x; j < OWORDS; j += 256) sh[j] = 0;
        __syncthreads();
        const int* src = edges + (size_t)(2 * m) * N_EDGES;
        const int beg = c * (N_EDGES / OCH);
        for (int i = beg + threadIdx.x; i < beg + (N_EDGES / OCH); i += 256) {
            const int s = src[i];
            atomicAdd(&sh[s >> 2], 1u << (8 * (s & 3)));
        }
        __syncthreads();
        uint* out = partials + (size_t)(m * OCH + c) * OWORDS;
        for (int j = threadIdx.x; j < OWORDS; j += 256) out[j] = sh[j];
    } else {
        const int local = blk - CONV_B - HIST_B - ODEG_B;
        const int base = local * (DIM * DIM / W1C_B);
        for (int i = base + threadIdx.x; i < base + DIM * DIM / W1C_B; i += 256)
            W1b[i] = (ushort)bf16rne(W1[i]);
    }
}

// ---------------------------------------------------------------------------
// K2: merged bucket scan (3 blocks, serial over 196) + nsrc merge.
__global__ __launch_bounds__(1024) void scan_nsrc_kernel(
        const int* __restrict__ bucket_cnt, int* __restrict__ bucket_off,
        int* __restrict__ bucket_cur, int* __restrict__ row_off,
        const uint* __restrict__ partials, float* __restrict__ nsrc) {
    const int blk = blockIdx.x;
    if (blk < N_META) {
        if (threadIdx.x == 0) {
            const int m = blk;
            int acc = 0;
            for (int b = 0; b < NBKT; ++b) {
                bucket_off[m * (NBKT + 1) + b] = acc;
                bucket_cur[m * NBKT + b] = acc;
                acc += bucket_cnt[m * NBKT + b];
            }
            bucket_off[m * (NBKT + 1) + NBKT] = acc;      // == N_EDGES
            row_off[m * (N_NODES + 1) + N_NODES] = N_EDGES;
        }
    } else {
        const int i = (blk - N_META) * 1024 + threadIdx.x;
        if (i < N_META * N_NODES) {
            const int m = i / N_NODES, node = i - m * N_NODES;
            const int q = node >> 2, s8 = 8 * (node & 3);
            int s = 0;
#pragma unroll
            for (int c = 0; c < OCH; ++c)
                s += (partials[(size_t)(m * OCH + c) * OWORDS + q] >> s8) & 0xFF;
            nsrc[i] = rsqrtf(fmaxf((float)s, 1.0f));
        }
    }
}

// ---------------------------------------------------------------------------
// K3: bin edges into dst-buckets as packed (dst<<16|src) pairs.
__global__ __launch_bounds__(256) void bin_kernel(
        const int* __restrict__ edges, int* __restrict__ bucket_cur,
        uint* __restrict__ pairs) {
    const int m = blockIdx.y;
    __shared__ int hist[NBKT];
    __shared__ int cur[NBKT];
    for (int j = threadIdx.x; j < NBKT; j += 256) hist[j] = 0;
    __syncthreads();
    const int* src = edges + (size_t)(2 * m) * N_EDGES;
    const int* dst = edges + (size_t)(2 * m + 1) * N_EDGES;
    const int beg = blockIdx.x * BIN_CHUNK;
    const int end = min(beg + BIN_CHUNK, N_EDGES);
    for (int i = beg + threadIdx.x; i < end; i += 256)
        atomicAdd(&hist[dst[i] >> 8], 1);
    __syncthreads();
    for (int j = threadIdx.x; j < NBKT; j += 256) {
        const int n = hist[j];
        cur[j] = n ? atomicAdd(&bucket_cur[m * NBKT + j], n) : 0;
    }
    __syncthreads();
    uint* pm = pairs + (size_t)m * N_EDGES;
    for (int i = beg + threadIdx.x; i < end; i += 256) {
        const uint d = (uint)dst[i];
        const int pos = atomicAdd(&cur[d >> 8], 1);
        pm[pos] = (d << 16) | (uint)src[i];
    }
}

// ---------------------------------------------------------------------------
// K4: finalize CSR per bucket (ushort src ids).
__global__ __launch_bounds__(256) void csr_kernel(
        const uint* __restrict__ pairs, const int* __restrict__ bucket_off,
        int* __restrict__ row_off, ushort* __restrict__ csr) {
    const int b = blockIdx.x, m = blockIdx.y;
    const int node_base = b * BKT;
    const int nb = min(BKT, N_NODES - node_base);
    __shared__ uint stage[CSR_CAP];
    __shared__ int hist[BKT];
    __shared__ int sc[BKT];
    __shared__ int cur[BKT];
    hist[threadIdx.x] = 0;
    __syncthreads();
    const int beg = bucket_off[m * (NBKT + 1) + b];
    const int end = bucket_off[m * (NBKT + 1) + b + 1];
    const int cnt = end - beg;
    const uint* pm = pairs + (size_t)m * N_EDGES + beg;
    for (int i = threadIdx.x; i < cnt; i += 256) {
        const uint p = pm[i];
        if (i < CSR_CAP) stage[i] = p;
        atomicAdd(&hist[(int)(p >> 16) - node_base], 1);
    }
    __syncthreads();
    const int v = hist[threadIdx.x];
    sc[threadIdx.x] = v;
    __syncthreads();
    for (int off = 1; off < BKT; off <<= 1) {
        const int t = (threadIdx.x >= off) ? sc[threadIdx.x - off] : 0;
        __syncthreads();
        sc[threadIdx.x] += t;
        __syncthreads();
    }
    const int excl = sc[threadIdx.x] - v;
    cur[threadIdx.x] = beg + excl;
    if (threadIdx.x < nb)
        row_off[m * (N_NODES + 1) + node_base + threadIdx.x] = beg + excl;
    __syncthreads();
    ushort* cm = csr + (size_t)m * N_EDGES;
    for (int i = threadIdx.x; i < cnt; i += 256) {
        const uint p = (i < CSR_CAP) ? stage[i] : pm[i];
        const int dl = (int)(p >> 16) - node_base;
        const int pos = atomicAdd(&cur[dl], 1);
        cm[pos] = (ushort)(p & 0xFFFFu);
    }
}

// ---------------------------------------------------------------------------
// K5: gather (bf16 h). One wave per dst node; half-wave covers a full 256B
// bf16 row, wave runs 2 edges/step, unroll-8 -> 16 edges in flight.
__global__ __launch_bounds__(256) void gather_kernel(
        const ushort* __restrict__ hb, const ushort* __restrict__ csr,
        const int* __restrict__ row_off, const float* __restrict__ nsrc,
        float* __restrict__ z) {
    const int m    = blockIdx.y;
    const int wave = threadIdx.x >> 6;
    const int lane = threadIdx.x & 63;
    const int half = lane >> 5;
    const int c    = lane & 31;              // dims 4c..4c+3
    const int node = blockIdx.x * 4 + wave;
    const int* ro = row_off + m * (N_NODES + 1);
    const int beg = ro[node];
    const int end = ro[node + 1];
    const ushort* srcs = csr + (size_t)m * N_EDGES;
    const float* ns = nsrc + m * N_NODES;
    float4 acc = {0.f, 0.f, 0.f, 0.f};
    int j = beg;
    for (; j + 16 <= end; j += 16) {
        int s[8]; float n[8]; uint2 hv[8];
#pragma unroll
        for (int u = 0; u < 8; ++u) s[u] = srcs[j + 2 * u + half];
#pragma unroll
        for (int u = 0; u < 8; ++u) {
            n[u]  = ns[s[u]];
            hv[u] = *reinterpret_cast<const uint2*>(hb + (size_t)s[u] * DIM + c * 4);
        }
#pragma unroll
        for (int u = 0; u < 8; ++u) {
            acc.x = fmaf(bflo(hv[u].x), n[u], acc.x);
            acc.y = fmaf(bfhi(hv[u].x), n[u], acc.y);
            acc.z = fmaf(bflo(hv[u].y), n[u], acc.z);
            acc.w = fmaf(bfhi(hv[u].y), n[u], acc.w);
        }
    }
    for (; j + 2 <= end; j += 2) {
        const int s0 = srcs[j + half];
        const float n0 = ns[s0];
        const uint2 h0 = *reinterpret_cast<const uint2*>(hb + (size_t)s0 * DIM + c * 4);
        acc.x = fmaf(bflo(h0.x), n0, acc.x);
        acc.y = fmaf(bfhi(h0.x), n0, acc.y);
        acc.z = fmaf(bflo(h0.y), n0, acc.z);
        acc.w = fmaf(bfhi(h0.y), n0, acc.w);
    }
    if (j < end && half == 0) {
        const int s0 = srcs[j];
        const float n0 = ns[s0];
        const uint2 h0 = *reinterpret_cast<const uint2*>(hb + (size_t)s0 * DIM + c * 4);
        acc.x = fmaf(bflo(h0.x), n0, acc.x);
        acc.y = fmaf(bfhi(h0.x), n0, acc.y);
        acc.z = fmaf(bflo(h0.y), n0, acc.z);
        acc.w = fmaf(bfhi(h0.y), n0, acc.w);
    }
    acc.x += __shfl_xor(acc.x, 32);
    acc.y += __shfl_xor(acc.y, 32);
    acc.z += __shfl_xor(acc.z, 32);
    acc.w += __shfl_xor(acc.w, 32);
    if (half == 0) {
        const float nd = rsqrtf(fmaxf((float)(end - beg), 1.0f));
        float4 o;
        o.x = acc.x * nd; o.y = acc.y * nd; o.z = acc.z * nd; o.w = acc.w * nd;
        *reinterpret_cast<float4*>(
            z + ((size_t)m * N_NODES + node) * DIM + c * 4) = o;
    }
}

// ---------------------------------------------------------------------------
// K6: semantic attention as LDS-tiled GEMM. Block = 64 nodes x 128 cols;
// thread = 8n x 4j register tile; zT (bf16, transposed) + W1 (bf16) in LDS.
__global__ __launch_bounds__(256) void attn_kernel(
        const float* __restrict__ z, const ushort* __restrict__ W1b,
        const float* __restrict__ b1, const float* __restrict__ W2,
        float* __restrict__ wacc) {
    const int m   = blockIdx.y;
    const int tid = threadIdx.x;
    __shared__ ushort zT[DIM * ZSTR];          // [d][n] bf16, stride 72
    __shared__ ushort w1s[DIM * DIM];          // [d][j] bf16
    __shared__ float red[4];

    // stage W1b (32KB) as uint4
    {
        const uint4* s = reinterpret_cast<const uint4*>(W1b);
        uint4* dst = reinterpret_cast<uint4*>(w1s);
        for (int i = tid; i < DIM * DIM / 8; i += 256) dst[i] = s[i];
    }
    // stage z tile transposed -> bf16
    const int node_base = blockIdx.x * AT_TILE;
    {
        const float4* zf = reinterpret_cast<const float4*>(z + (size_t)m * N_NODES * DIM);
        for (int i = tid; i < AT_TILE * (DIM / 4); i += 256) {
            const int n = i >> 5, dq = i & 31;
            int row = node_base + n;
            if (row >= N_NODES) row = N_NODES - 1;
            const float4 v = zf[(size_t)row * (DIM / 4) + dq];
            zT[(4 * dq + 0) * ZSTR + n] = (ushort)bf16rne(v.x);
            zT[(4 * dq + 1) * ZSTR + n] = (ushort)bf16rne(v.y);
            zT[(4 * dq + 2) * ZSTR + n] = (ushort)bf16rne(v.z);
            zT[(4 * dq + 3) * ZSTR + n] = (ushort)bf16rne(v.w);
        }
    }
    __syncthreads();

    const int jb = (tid & 31) * 4;             // 4 output cols
    const int nb = (tid >> 5) * 8;             // 8 nodes
    float q[8][4] = {};
    for (int d = 0; d < DIM; ++d) {
        const uint4 zp = *reinterpret_cast<const uint4*>(&zT[d * ZSTR + nb]);
        const uint2 wp = *reinterpret_cast<const uint2*>(&w1s[d * DIM + jb]);
        float zv[8];
        zv[0] = bflo(zp.x); zv[1] = bfhi(zp.x);
        zv[2] = bflo(zp.y); zv[3] = bfhi(zp.y);
        zv[4] = bflo(zp.z); zv[5] = bfhi(zp.z);
        zv[6] = bflo(zp.w); zv[7] = bfhi(zp.w);
        float wv[4];
        wv[0] = bflo(wp.x); wv[1] = bfhi(wp.x);
        wv[2] = bflo(wp.y); wv[3] = bfhi(wp.y);
#pragma unroll
        for (int i = 0; i < 8; ++i) {
            q[i][0] = fmaf(zv[i], wv[0], q[i][0]);
            q[i][1] = fmaf(zv[i], wv[1], q[i][1]);
            q[i][2] = fmaf(zv[i], wv[2], q[i][2]);
            q[i][3] = fmaf(zv[i], wv[3], q[i][3]);
        }
    }
    const float4 bv  = *reinterpret_cast<const float4*>(b1 + jb);
    const float4 w2v = *reinterpret_cast<const float4*>(W2 + jb);
    float local = 0.0f;
#pragma unroll
    for (int i = 0; i < 8; ++i) {
        if (node_base + nb + i < N_NODES) {
            local += tanhf(q[i][0] + bv.x) * w2v.x;
            local += tanhf(q[i][1] + bv.y) * w2v.y;
            local += tanhf(q[i][2] + bv.z) * w2v.z;
            local += tanhf(q[i][3] + bv.w) * w2v.w;
        }
    }
    for (int off = 32; off > 0; off >>= 1)
        local += __shfl_xor(local, off);
    const int wv_id = tid >> 6;
    if ((tid & 63) == 0) red[wv_id] = local;
    __syncthreads();
    if (tid == 0)
        atomicAdd(&wacc[m], red[0] + red[1] + red[2] + red[3]);
}

// ---------------------------------------------------------------------------
// K7: softmax over 3 scores + beta-weighted sum.
__global__ __launch_bounds__(256) void final_kernel(
        const float* __restrict__ z, const float* __restrict__ wacc,
        float* __restrict__ out) {
    const int g = blockIdx.x * 256 + threadIdx.x;      // float4 index
    if (g >= N_NODES * DIM / 4) return;
    const float invN = 1.0f / (float)N_NODES;
    const float w0 = wacc[0] * invN, w1 = wacc[1] * invN, w2 = wacc[2] * invN;
    const float mx = fmaxf(w0, fmaxf(w1, w2));
    const float e0 = expf(w0 - mx), e1 = expf(w1 - mx), e2 = expf(w2 - mx);
    const float inv = 1.0f / (e0 + e1 + e2);
    const float beta[3] = {e0 * inv, e1 * inv, e2 * inv};
    float4 acc = {0.f, 0.f, 0.f, 0.f};
#pragma unroll
    for (int m = 0; m < N_META; ++m) {
        const float4 zv = *reinterpret_cast<const float4*>(
            z + ((size_t)m * N_NODES) * DIM + (size_t)g * 4);
        acc.x = fmaf(zv.x, beta[m], acc.x);
        acc.y = fmaf(zv.y, beta[m], acc.y);
        acc.z = fmaf(zv.z, beta[m], acc.z);
        acc.w = fmaf(zv.w, beta[m], acc.w);
    }
    *reinterpret_cast<float4*>(out + (size_t)g * 4) = acc;
}

extern "C" void kernel_launch(void* const* d_in, const int* in_sizes, int n_in,
                              void* d_out, int out_size, void* d_ws, size_t ws_size,
                              hipStream_t stream) {
    const float* h    = (const float*)d_in[0];
    const int*  edges = (const int*)d_in[1];
    const float* W1   = (const float*)d_in[2];
    const float* b1   = (const float*)d_in[3];
    const float* W2   = (const float*)d_in[4];
    float* out = (float*)d_out;

    // ws (~100MB): z[76.8MB] region hosts pairs[19.2MB]+partials[2.4MB] early
    // (both dead before gather writes z) | hb | csr | row_off | nsrc | small
    char* p = (char*)d_ws;
    float* z        = (float*)p;
    uint*  pairs    = (uint*)p;
    uint*  partials = (uint*)(p + (size_t)N_META * N_EDGES * 4);
    p += (size_t)N_META * N_NODES * DIM * 4;
    ushort* hb      = (ushort*)p; p += (size_t)N_NODES * DIM * 2;
    ushort* csr     = (ushort*)p; p += (size_t)N_META * N_EDGES * 2;
    int* row_off    = (int*)p;    p += ((size_t)N_META * (N_NODES + 1) + 1) * 4;
    float* nsrc     = (float*)p;  p += (size_t)N_META * N_NODES * 4;
    float* wacc     = (float*)p;  p += 16 * 4;
    int* bucket_cnt = (int*)p;    p += (size_t)N_META * NBKT * 4;
    int* bucket_off = (int*)p;    p += (size_t)N_META * (NBKT + 1) * 4 + 4;
    int* bucket_cur = (int*)p;    p += (size_t)N_META * NBKT * 4;
    ushort* W1b     = (ushort*)p; p += (size_t)DIM * DIM * 2;

    // zero wacc + bucket_cnt (contiguous)
    hipMemsetAsync(wacc, 0, (16 + (size_t)N_META * NBKT) * 4, stream);

    prep_kernel<<<dim3(CONV_B + HIST_B + ODEG_B + W1C_B), 256, 0, stream>>>(
        h, edges, W1, hb, bucket_cnt, partials, W1b);
    scan_nsrc_kernel<<<dim3(N_META + (N_META * N_NODES + 1023) / 1024), 1024, 0, stream>>>(
        bucket_cnt, bucket_off, bucket_cur, row_off, partials, nsrc);
    bin_kernel<<<dim3(NCHUNK, N_META), 256, 0, stream>>>(edges, bucket_cur, pairs);
    csr_kernel<<<dim3(NBKT, N_META), 256, 0, stream>>>(pairs, bucket_off, row_off, csr);
    gather_kernel<<<dim3(N_NODES / 4, N_META), 256, 0, stream>>>(
        hb, csr, row_off, nsrc, z);
    attn_kernel<<<dim3(AT_NBLK, N_META), 256, 0, stream>>>(z, W1b, b1, W2, wacc);
    final_kernel<<<dim3((N_NODES * DIM / 4 + 255) / 256), 256, 0, stream>>>(z, wacc, out);
}

// Round 7
// 544.431 us; speedup vs baseline: 16.1839x; 1.1449x over previous
//
#include <hip/hip_runtime.h>
#include <cstdint>
#include <cstddef>

typedef unsigned int  uint;
typedef unsigned short ushort;

#define N_NODES 50000
#define N_EDGES 1600000
#define N_META  3
#define DIM     128

#define BKT       256                 // dst nodes per bucket
#define NBKT      196                 // ceil(N_NODES / BKT)
#define BIN_CHUNK 16384
#define NCHUNK    98                  // ceil(N_EDGES / BIN_CHUNK)
#define CSR_CAP   10240               // bucket mean 8192, +22 sigma
#define CONV_B    160                 // prep role block ranges
#define HIST_B    192                 // 64 per metapath
#define OCH       32                  // out-degree edge chunks
#define NRANGE    4                   // out-degree node ranges
#define ODEG_B    (OCH * NRANGE * N_META)   // 384
#define W1C_B     4                   // W1 fp32 -> bf16
#define ORANGE    12500               // nodes per out-degree range
#define RWORDS    3125                // ORANGE/4 byte-packed words (12.5KB)
#define OWORDS    12500               // 50000 nodes / 4 per uint

#define AT_TILE   64                  // attn: nodes per block
#define AT_NBLK   782                 // ceil(N_NODES / AT_TILE)
#define ZSTR      72                  // zT row stride (ushorts), 16B-aligned rows

__device__ __forceinline__ uint bf16rne(float f) {
    const uint u = __float_as_uint(f);
    return (u + 0x7FFFu + ((u >> 16) & 1u)) >> 16;
}
__device__ __forceinline__ float bflo(uint p) { return __uint_as_float(p << 16); }
__device__ __forceinline__ float bfhi(uint p) { return __uint_as_float(p & 0xFFFF0000u); }

// ---------------------------------------------------------------------------
// K1: merged prep — role by block range. LDS capped at 12.8KB (12 blocks/CU).
//   [0,CONV_B)    : h fp32 -> hb bf16
//   [..,+HIST_B)  : per-bucket dst histogram (LDS 784B of union)
//   [..,+ODEG_B)  : out-degree, byte-packed SUB-RANGE histogram (12.5KB):
//                   block = (m, chunk of 50K edges, range of 12500 nodes)
//   [..,+W1C_B)   : W1 fp32 -> bf16
__global__ __launch_bounds__(256) void prep_kernel(
        const float* __restrict__ h, const int* __restrict__ edges,
        const float* __restrict__ W1, ushort* __restrict__ hb,
        int* __restrict__ bucket_cnt, uint* __restrict__ partials,
        ushort* __restrict__ W1b) {
    __shared__ uint sh[RWORDS + 75];          // 12.8KB union
    const int blk = blockIdx.x;
    if (blk < CONV_B) {
        const int total = N_NODES * DIM / 4;
        for (int i = blk * 256 + threadIdx.x; i < total; i += CONV_B * 256) {
            const float4 v = reinterpret_cast<const float4*>(h)[i];
            uint2 o;
            o.x = bf16rne(v.x) | (bf16rne(v.y) << 16);
            o.y = bf16rne(v.z) | (bf16rne(v.w) << 16);
            reinterpret_cast<uint2*>(hb)[i] = o;
        }
    } else if (blk < CONV_B + HIST_B) {
        const int b2 = blk - CONV_B;
        const int m = b2 >> 6, c = b2 & 63;
        for (int j = threadIdx.x; j < NBKT; j += 256) sh[j] = 0;
        __syncthreads();
        const int* dst = edges + (size_t)(2 * m + 1) * N_EDGES;
        const int beg = c * (N_EDGES / 64);
        for (int i = beg + threadIdx.x; i < beg + (N_EDGES / 64); i += 256)
            atomicAdd(&sh[dst[i] >> 8], 1u);
        __syncthreads();
        for (int j = threadIdx.x; j < NBKT; j += 256)
            if (sh[j]) atomicAdd(&bucket_cnt[m * NBKT + j], (int)sh[j]);
    } else if (blk < CONV_B + HIST_B + ODEG_B) {
        const int b3 = blk - CONV_B - HIST_B;     // 0..383
        const int m   = b3 >> 7;                  // 128 blocks per metapath
        const int rem = b3 & 127;
        const int c   = rem >> 2;                 // chunk 0..31
        const int r   = rem & 3;                  // range 0..3
        for (int j = threadIdx.x; j < RWORDS; j += 256) sh[j] = 0;
        __syncthreads();
        const int* src = edges + (size_t)(2 * m) * N_EDGES;
        const int beg = c * (N_EDGES / OCH);
        const int rbase = r * ORANGE;
        for (int i = beg + threadIdx.x; i < beg + (N_EDGES / OCH); i += 256) {
            const unsigned u = (unsigned)(src[i] - rbase);
            if (u < (unsigned)ORANGE)
                atomicAdd(&sh[u >> 2], 1u << (8 * (u & 3)));
        }
        __syncthreads();
        uint* out = partials + (size_t)(m * OCH + c) * OWORDS + r * RWORDS;
        for (int j = threadIdx.x; j < RWORDS; j += 256) out[j] = sh[j];
    } else {
        const int local = blk - CONV_B - HIST_B - ODEG_B;
        const int base = local * (DIM * DIM / W1C_B);
        for (int i = base + threadIdx.x; i < base + DIM * DIM / W1C_B; i += 256)
            W1b[i] = (ushort)bf16rne(W1[i]);
    }
}

// ---------------------------------------------------------------------------
// K2: merged bucket scan (3 blocks, serial over 196) + nsrc merge (32 chunks).
__global__ __launch_bounds__(1024) void scan_nsrc_kernel(
        const int* __restrict__ bucket_cnt, int* __restrict__ bucket_off,
        int* __restrict__ bucket_cur, int* __restrict__ row_off,
        const uint* __restrict__ partials, float* __restrict__ nsrc) {
    const int blk = blockIdx.x;
    if (blk < N_META) {
        if (threadIdx.x == 0) {
            const int m = blk;
            int acc = 0;
            for (int b = 0; b < NBKT; ++b) {
                bucket_off[m * (NBKT + 1) + b] = acc;
                bucket_cur[m * NBKT + b] = acc;
                acc += bucket_cnt[m * NBKT + b];
            }
            bucket_off[m * (NBKT + 1) + NBKT] = acc;      // == N_EDGES
            row_off[m * (N_NODES + 1) + N_NODES] = N_EDGES;
        }
    } else {
        const int i = (blk - N_META) * 1024 + threadIdx.x;
        if (i < N_META * N_NODES) {
            const int m = i / N_NODES, node = i - m * N_NODES;
            const int q = node >> 2, s8 = 8 * (node & 3);
            int s = 0;
#pragma unroll
            for (int c = 0; c < OCH; ++c)
                s += (partials[(size_t)(m * OCH + c) * OWORDS + q] >> s8) & 0xFF;
            nsrc[i] = rsqrtf(fmaxf((float)s, 1.0f));
        }
    }
}

// ---------------------------------------------------------------------------
// K3: bin edges into dst-buckets as packed (dst<<16|src) pairs.
__global__ __launch_bounds__(256) void bin_kernel(
        const int* __restrict__ edges, int* __restrict__ bucket_cur,
        uint* __restrict__ pairs) {
    const int m = blockIdx.y;
    __shared__ int hist[NBKT];
    __shared__ int cur[NBKT];
    for (int j = threadIdx.x; j < NBKT; j += 256) hist[j] = 0;
    __syncthreads();
    const int* src = edges + (size_t)(2 * m) * N_EDGES;
    const int* dst = edges + (size_t)(2 * m + 1) * N_EDGES;
    const int beg = blockIdx.x * BIN_CHUNK;
    const int end = min(beg + BIN_CHUNK, N_EDGES);
    for (int i = beg + threadIdx.x; i < end; i += 256)
        atomicAdd(&hist[dst[i] >> 8], 1);
    __syncthreads();
    for (int j = threadIdx.x; j < NBKT; j += 256) {
        const int n = hist[j];
        cur[j] = n ? atomicAdd(&bucket_cur[m * NBKT + j], n) : 0;
    }
    __syncthreads();
    uint* pm = pairs + (size_t)m * N_EDGES;
    for (int i = beg + threadIdx.x; i < end; i += 256) {
        const uint d = (uint)dst[i];
        const int pos = atomicAdd(&cur[d >> 8], 1);
        pm[pos] = (d << 16) | (uint)src[i];
    }
}

// ---------------------------------------------------------------------------
// K4: finalize CSR per bucket (ushort src ids).
__global__ __launch_bounds__(256) void csr_kernel(
        const uint* __restrict__ pairs, const int* __restrict__ bucket_off,
        int* __restrict__ row_off, ushort* __restrict__ csr) {
    const int b = blockIdx.x, m = blockIdx.y;
    const int node_base = b * BKT;
    const int nb = min(BKT, N_NODES - node_base);
    __shared__ uint stage[CSR_CAP];
    __shared__ int hist[BKT];
    __shared__ int sc[BKT];
    __shared__ int cur[BKT];
    hist[threadIdx.x] = 0;
    __syncthreads();
    const int beg = bucket_off[m * (NBKT + 1) + b];
    const int end = bucket_off[m * (NBKT + 1) + b + 1];
    const int cnt = end - beg;
    const uint* pm = pairs + (size_t)m * N_EDGES + beg;
    for (int i = threadIdx.x; i < cnt; i += 256) {
        const uint p = pm[i];
        if (i < CSR_CAP) stage[i] = p;
        atomicAdd(&hist[(int)(p >> 16) - node_base], 1);
    }
    __syncthreads();
    const int v = hist[threadIdx.x];
    sc[threadIdx.x] = v;
    __syncthreads();
    for (int off = 1; off < BKT; off <<= 1) {
        const int t = (threadIdx.x >= off) ? sc[threadIdx.x - off] : 0;
        __syncthreads();
        sc[threadIdx.x] += t;
        __syncthreads();
    }
    const int excl = sc[threadIdx.x] - v;
    cur[threadIdx.x] = beg + excl;
    if (threadIdx.x < nb)
        row_off[m * (N_NODES + 1) + node_base + threadIdx.x] = beg + excl;
    __syncthreads();
    ushort* cm = csr + (size_t)m * N_EDGES;
    for (int i = threadIdx.x; i < cnt; i += 256) {
        const uint p = (i < CSR_CAP) ? stage[i] : pm[i];
        const int dl = (int)(p >> 16) - node_base;
        const int pos = atomicAdd(&cur[dl], 1);
        cm[pos] = (ushort)(p & 0xFFFFu);
    }
}

// ---------------------------------------------------------------------------
// K5: gather (bf16 h). One wave per dst node; half-wave covers a full 256B
// bf16 row, wave runs 2 edges/step, unroll-8 -> 16 edges in flight.
__global__ __launch_bounds__(256) void gather_kernel(
        const ushort* __restrict__ hb, const ushort* __restrict__ csr,
        const int* __restrict__ row_off, const float* __restrict__ nsrc,
        float* __restrict__ z) {
    const int m    = blockIdx.y;
    const int wave = threadIdx.x >> 6;
    const int lane = threadIdx.x & 63;
    const int half = lane >> 5;
    const int c    = lane & 31;              // dims 4c..4c+3
    const int node = blockIdx.x * 4 + wave;
    const int* ro = row_off + m * (N_NODES + 1);
    const int beg = ro[node];
    const int end = ro[node + 1];
    const ushort* srcs = csr + (size_t)m * N_EDGES;
    const float* ns = nsrc + m * N_NODES;
    float4 acc = {0.f, 0.f, 0.f, 0.f};
    int j = beg;
    for (; j + 16 <= end; j += 16) {
        int s[8]; float n[8]; uint2 hv[8];
#pragma unroll
        for (int u = 0; u < 8; ++u) s[u] = srcs[j + 2 * u + half];
#pragma unroll
        for (int u = 0; u < 8; ++u) {
            n[u]  = ns[s[u]];
            hv[u] = *reinterpret_cast<const uint2*>(hb + (size_t)s[u] * DIM + c * 4);
        }
#pragma unroll
        for (int u = 0; u < 8; ++u) {
            acc.x = fmaf(bflo(hv[u].x), n[u], acc.x);
            acc.y = fmaf(bfhi(hv[u].x), n[u], acc.y);
            acc.z = fmaf(bflo(hv[u].y), n[u], acc.z);
            acc.w = fmaf(bfhi(hv[u].y), n[u], acc.w);
        }
    }
    for (; j + 2 <= end; j += 2) {
        const int s0 = srcs[j + half];
        const float n0 = ns[s0];
        const uint2 h0 = *reinterpret_cast<const uint2*>(hb + (size_t)s0 * DIM + c * 4);
        acc.x = fmaf(bflo(h0.x), n0, acc.x);
        acc.y = fmaf(bfhi(h0.x), n0, acc.y);
        acc.z = fmaf(bflo(h0.y), n0, acc.z);
        acc.w = fmaf(bfhi(h0.y), n0, acc.w);
    }
    if (j < end && half == 0) {
        const int s0 = srcs[j];
        const float n0 = ns[s0];
        const uint2 h0 = *reinterpret_cast<const uint2*>(hb + (size_t)s0 * DIM + c * 4);
        acc.x = fmaf(bflo(h0.x), n0, acc.x);
        acc.y = fmaf(bfhi(h0.x), n0, acc.y);
        acc.z = fmaf(bflo(h0.y), n0, acc.z);
        acc.w = fmaf(bfhi(h0.y), n0, acc.w);
    }
    acc.x += __shfl_xor(acc.x, 32);
    acc.y += __shfl_xor(acc.y, 32);
    acc.z += __shfl_xor(acc.z, 32);
    acc.w += __shfl_xor(acc.w, 32);
    if (half == 0) {
        const float nd = rsqrtf(fmaxf((float)(end - beg), 1.0f));
        float4 o;
        o.x = acc.x * nd; o.y = acc.y * nd; o.z = acc.z * nd; o.w = acc.w * nd;
        *reinterpret_cast<float4*>(
            z + ((size_t)m * N_NODES + node) * DIM + c * 4) = o;
    }
}

// ---------------------------------------------------------------------------
// K6: semantic attention as LDS-tiled GEMM. Block = 64 nodes x 128 cols;
// thread = 8n x 4j register tile; zT (bf16, transposed) + W1 (bf16) in LDS.
__global__ __launch_bounds__(256) void attn_kernel(
        const float* __restrict__ z, const ushort* __restrict__ W1b,
        const float* __restrict__ b1, const float* __restrict__ W2,
        float* __restrict__ wacc) {
    const int m   = blockIdx.y;
    const int tid = threadIdx.x;
    __shared__ ushort zT[DIM * ZSTR];          // [d][n] bf16, stride 72
    __shared__ ushort w1s[DIM * DIM];          // [d][j] bf16
    __shared__ float red[4];

    {
        const uint4* s = reinterpret_cast<const uint4*>(W1b);
        uint4* dst = reinterpret_cast<uint4*>(w1s);
        for (int i = tid; i < DIM * DIM / 8; i += 256) dst[i] = s[i];
    }
    const int node_base = blockIdx.x * AT_TILE;
    {
        const float4* zf = reinterpret_cast<const float4*>(z + (size_t)m * N_NODES * DIM);
        for (int i = tid; i < AT_TILE * (DIM / 4); i += 256) {
            const int n = i >> 5, dq = i & 31;
            int row = node_base + n;
            if (row >= N_NODES) row = N_NODES - 1;
            const float4 v = zf[(size_t)row * (DIM / 4) + dq];
            zT[(4 * dq + 0) * ZSTR + n] = (ushort)bf16rne(v.x);
            zT[(4 * dq + 1) * ZSTR + n] = (ushort)bf16rne(v.y);
            zT[(4 * dq + 2) * ZSTR + n] = (ushort)bf16rne(v.z);
            zT[(4 * dq + 3) * ZSTR + n] = (ushort)bf16rne(v.w);
        }
    }
    __syncthreads();

    const int jb = (tid & 31) * 4;             // 4 output cols
    const int nb = (tid >> 5) * 8;             // 8 nodes
    float q[8][4] = {};
    for (int d = 0; d < DIM; ++d) {
        const uint4 zp = *reinterpret_cast<const uint4*>(&zT[d * ZSTR + nb]);
        const uint2 wp = *reinterpret_cast<const uint2*>(&w1s[d * DIM + jb]);
        float zv[8];
        zv[0] = bflo(zp.x); zv[1] = bfhi(zp.x);
        zv[2] = bflo(zp.y); zv[3] = bfhi(zp.y);
        zv[4] = bflo(zp.z); zv[5] = bfhi(zp.z);
        zv[6] = bflo(zp.w); zv[7] = bfhi(zp.w);
        float wv[4];
        wv[0] = bflo(wp.x); wv[1] = bfhi(wp.x);
        wv[2] = bflo(wp.y); wv[3] = bfhi(wp.y);
#pragma unroll
        for (int i = 0; i < 8; ++i) {
            q[i][0] = fmaf(zv[i], wv[0], q[i][0]);
            q[i][1] = fmaf(zv[i], wv[1], q[i][1]);
            q[i][2] = fmaf(zv[i], wv[2], q[i][2]);
            q[i][3] = fmaf(zv[i], wv[3], q[i][3]);
        }
    }
    const float4 bv  = *reinterpret_cast<const float4*>(b1 + jb);
    const float4 w2v = *reinterpret_cast<const float4*>(W2 + jb);
    float local = 0.0f;
#pragma unroll
    for (int i = 0; i < 8; ++i) {
        if (node_base + nb + i < N_NODES) {
            local += tanhf(q[i][0] + bv.x) * w2v.x;
            local += tanhf(q[i][1] + bv.y) * w2v.y;
            local += tanhf(q[i][2] + bv.z) * w2v.z;
            local += tanhf(q[i][3] + bv.w) * w2v.w;
        }
    }
    for (int off = 32; off > 0; off >>= 1)
        local += __shfl_xor(local, off);
    const int wv_id = tid >> 6;
    if ((tid & 63) == 0) red[wv_id] = local;
    __syncthreads();
    if (tid == 0)
        atomicAdd(&wacc[m], red[0] + red[1] + red[2] + red[3]);
}

// ---------------------------------------------------------------------------
// K7: softmax over 3 scores + beta-weighted sum.
__global__ __launch_bounds__(256) void final_kernel(
        const float* __restrict__ z, const float* __restrict__ wacc,
        float* __restrict__ out) {
    const int g = blockIdx.x * 256 + threadIdx.x;      // float4 index
    if (g >= N_NODES * DIM / 4) return;
    const float invN = 1.0f / (float)N_NODES;
    const float w0 = wacc[0] * invN, w1 = wacc[1] * invN, w2 = wacc[2] * invN;
    const float mx = fmaxf(w0, fmaxf(w1, w2));
    const float e0 = expf(w0 - mx), e1 = expf(w1 - mx), e2 = expf(w2 - mx);
    const float inv = 1.0f / (e0 + e1 + e2);
    const float beta[3] = {e0 * inv, e1 * inv, e2 * inv};
    float4 acc = {0.f, 0.f, 0.f, 0.f};
#pragma unroll
    for (int m = 0; m < N_META; ++m) {
        const float4 zv = *reinterpret_cast<const float4*>(
            z + ((size_t)m * N_NODES) * DIM + (size_t)g * 4);
        acc.x = fmaf(zv.x, beta[m], acc.x);
        acc.y = fmaf(zv.y, beta[m], acc.y);
        acc.z = fmaf(zv.z, beta[m], acc.z);
        acc.w = fmaf(zv.w, beta[m], acc.w);
    }
    *reinterpret_cast<float4*>(out + (size_t)g * 4) = acc;
}

extern "C" void kernel_launch(void* const* d_in, const int* in_sizes, int n_in,
                              void* d_out, int out_size, void* d_ws, size_t ws_size,
                              hipStream_t stream) {
    const float* h    = (const float*)d_in[0];
    const int*  edges = (const int*)d_in[1];
    const float* W1   = (const float*)d_in[2];
    const float* b1   = (const float*)d_in[3];
    const float* W2   = (const float*)d_in[4];
    float* out = (float*)d_out;

    // ws (~100MB): z[76.8MB] region hosts pairs[19.2MB]+partials[4.8MB] early
    // (both dead before gather writes z) | hb | csr | row_off | nsrc | small
    char* p = (char*)d_ws;
    float* z        = (float*)p;
    uint*  pairs    = (uint*)p;
    uint*  partials = (uint*)(p + (size_t)N_META * N_EDGES * 4);
    p += (size_t)N_META * N_NODES * DIM * 4;
    ushort* hb      = (ushort*)p; p += (size_t)N_NODES * DIM * 2;
    ushort* csr     = (ushort*)p; p += (size_t)N_META * N_EDGES * 2;
    int* row_off    = (int*)p;    p += ((size_t)N_META * (N_NODES + 1) + 1) * 4;
    float* nsrc     = (float*)p;  p += (size_t)N_META * N_NODES * 4;
    float* wacc     = (float*)p;  p += 16 * 4;
    int* bucket_cnt = (int*)p;    p += (size_t)N_META * NBKT * 4;
    int* bucket_off = (int*)p;    p += (size_t)N_META * (NBKT + 1) * 4 + 4;
    int* bucket_cur = (int*)p;    p += (size_t)N_META * NBKT * 4;
    ushort* W1b     = (ushort*)p; p += (size_t)DIM * DIM * 2;

    // zero wacc + bucket_cnt (contiguous)
    hipMemsetAsync(wacc, 0, (16 + (size_t)N_META * NBKT) * 4, stream);

    prep_kernel<<<dim3(CONV_B + HIST_B + ODEG_B + W1C_B), 256, 0, stream>>>(
        h, edges, W1, hb, bucket_cnt, partials, W1b);
    scan_nsrc_kernel<<<dim3(N_META + (N_META * N_NODES + 1023) / 1024), 1024, 0, stream>>>(
        bucket_cnt, bucket_off, bucket_cur, row_off, partials, nsrc);
    bin_kernel<<<dim3(NCHUNK, N_META), 256, 0, stream>>>(edges, bucket_cur, pairs);
    csr_kernel<<<dim3(NBKT, N_META), 256, 0, stream>>>(pairs, bucket_off, row_off, csr);
    gather_kernel<<<dim3(N_NODES / 4, N_META), 256, 0, stream>>>(
        hb, csr, row_off, nsrc, z);
    attn_kernel<<<dim3(AT_NBLK, N_META), 256, 0, stream>>>(z, W1b, b1, W2, wacc);
    final_kernel<<<dim3((N_NODES * DIM / 4 + 255) / 256), 256, 0, stream>>>(z, wacc, out);
}